// Round 1
// baseline (1272.243 us; speedup 1.0000x reference)
//
#include <hip/hip_runtime.h>
#include <hip/hip_bf16.h>

// Problem constants
// B=32, N=512, C=32, NT=24 -> IN=768; H=8, DH=48, E=384; OUT=768
// R = B*N = 16384 rows; QKV cols = 3*E = 1152

// ---------------------------------------------------------------------------
// Generic fp32 GEMM: C[m,n] = bias[n] + sum_k A[m,k]*Bw[k,n]
// BM=BN=128, BK=16, 256 threads, 8x8 micro-tile per thread.
// M % 128 == 0, N % 128 == 0, K % 16 == 0 (all true here).
// ---------------------------------------------------------------------------
__global__ __launch_bounds__(256) void gemm_bias(
    const float* __restrict__ A, const float* __restrict__ Bw,
    const float* __restrict__ bias, float* __restrict__ C,
    int M, int N, int K)
{
    __shared__ float As[16][132];   // [k][m], padded
    __shared__ float Bs[16][128];   // [k][n]
    const int tid = threadIdx.x;
    const int m0 = blockIdx.x * 128;
    const int n0 = blockIdx.y * 128;
    const int tx = tid & 15;
    const int ty = tid >> 4;

    float acc[8][8];
#pragma unroll
    for (int i = 0; i < 8; ++i)
#pragma unroll
        for (int j = 0; j < 8; ++j) acc[i][j] = 0.f;

    for (int k0 = 0; k0 < K; k0 += 16) {
        // A tile: 128 rows x 16 k -> 512 float4, 2 per thread, store transposed
#pragma unroll
        for (int i = 0; i < 2; ++i) {
            int idx = tid + 256 * i;
            int row = idx >> 2;
            int kq  = idx & 3;
            float4 v = *(const float4*)(A + (size_t)(m0 + row) * K + k0 + kq * 4);
            As[kq * 4 + 0][row] = v.x;
            As[kq * 4 + 1][row] = v.y;
            As[kq * 4 + 2][row] = v.z;
            As[kq * 4 + 3][row] = v.w;
        }
        // B tile: 16 k x 128 n -> 512 float4
#pragma unroll
        for (int i = 0; i < 2; ++i) {
            int idx = tid + 256 * i;
            int kr = idx >> 5;
            int cq = idx & 31;
            *(float4*)&Bs[kr][cq * 4] =
                *(const float4*)(Bw + (size_t)(k0 + kr) * N + n0 + cq * 4);
        }
        __syncthreads();
#pragma unroll
        for (int kk = 0; kk < 16; ++kk) {
            float a[8], b[8];
            *(float4*)&a[0] = *(const float4*)&As[kk][ty * 8];
            *(float4*)&a[4] = *(const float4*)&As[kk][ty * 8 + 4];
            *(float4*)&b[0] = *(const float4*)&Bs[kk][tx * 8];
            *(float4*)&b[4] = *(const float4*)&Bs[kk][tx * 8 + 4];
#pragma unroll
            for (int i = 0; i < 8; ++i)
#pragma unroll
                for (int j = 0; j < 8; ++j)
                    acc[i][j] = fmaf(a[i], b[j], acc[i][j]);
        }
        __syncthreads();
    }
#pragma unroll
    for (int i = 0; i < 8; ++i) {
        int m = m0 + ty * 8 + i;
#pragma unroll
        for (int j = 0; j < 8; j += 4) {
            int n = n0 + tx * 8 + j;
            float4 bv = *(const float4*)(bias + n);
            float4 o;
            o.x = acc[i][j + 0] + bv.x;
            o.y = acc[i][j + 1] + bv.y;
            o.z = acc[i][j + 2] + bv.z;
            o.w = acc[i][j + 3] + bv.w;
            *(float4*)(C + (size_t)m * N + n) = o;
        }
    }
}

// ---------------------------------------------------------------------------
// Temporal flash attention. qkv layout: [16384][1152], col = which*384+h*48+d.
// One thread = one q row (frame). Block: 256 threads. Grid: (2, H=8, B=32).
// Writes x_t to xcat cols [0,384): xcat[(b*512+f)*768 + h*48 + d]
// ---------------------------------------------------------------------------
__global__ __launch_bounds__(256) void attn_temporal(
    const float* __restrict__ qkv, float* __restrict__ xcat)
{
    const int b = blockIdx.z;
    const int h = blockIdx.y;
    const int f = blockIdx.x * 256 + threadIdx.x;

    __shared__ float Ks[32][48];
    __shared__ float Vs[32][48];

    const size_t qoff = ((size_t)(b * 512 + f)) * 1152 + h * 48;
    float4 q4[12], o4[12];
#pragma unroll
    for (int i = 0; i < 12; ++i) {
        q4[i] = *(const float4*)(qkv + qoff + i * 4);
        o4[i] = make_float4(0.f, 0.f, 0.f, 0.f);
    }
    float mrun = -3.0e38f, lrun = 0.f;
    const float scale = 0.14433756729740643f; // 1/sqrt(48)

    for (int t0 = 0; t0 < 512; t0 += 32) {
        __syncthreads();
        // stage K and V tiles: 32 rows x 12 float4 = 384 float4 each
#pragma unroll
        for (int i = 0; i < 2; ++i) {
            int idx = threadIdx.x + 256 * i;
            if (idx < 384) {
                int row = idx / 12;
                int c4  = idx % 12;
                const float* src = qkv + ((size_t)(b * 512 + t0 + row)) * 1152
                                       + 384 + h * 48 + c4 * 4;
                *(float4*)&Ks[row][c4 * 4] = *(const float4*)src;
                *(float4*)&Vs[row][c4 * 4] = *(const float4*)(src + 384);
            }
        }
        __syncthreads();

        float s[32];
#pragma unroll
        for (int j = 0; j < 32; ++j) {
            float4 acc = make_float4(0.f, 0.f, 0.f, 0.f);
#pragma unroll
            for (int dq = 0; dq < 12; ++dq) {
                float4 kv = *(const float4*)&Ks[j][dq * 4];
                acc.x = fmaf(q4[dq].x, kv.x, acc.x);
                acc.y = fmaf(q4[dq].y, kv.y, acc.y);
                acc.z = fmaf(q4[dq].z, kv.z, acc.z);
                acc.w = fmaf(q4[dq].w, kv.w, acc.w);
            }
            s[j] = (acc.x + acc.y + acc.z + acc.w) * scale;
        }
        float tmax = s[0];
#pragma unroll
        for (int j = 1; j < 32; ++j) tmax = fmaxf(tmax, s[j]);
        float newm = fmaxf(mrun, tmax);
        float corr = __expf(mrun - newm);
        lrun *= corr;
#pragma unroll
        for (int i = 0; i < 12; ++i) {
            o4[i].x *= corr; o4[i].y *= corr; o4[i].z *= corr; o4[i].w *= corr;
        }
#pragma unroll
        for (int j = 0; j < 32; ++j) {
            float p = __expf(s[j] - newm);
            lrun += p;
#pragma unroll
            for (int dq = 0; dq < 12; ++dq) {
                float4 vv = *(const float4*)&Vs[j][dq * 4];
                o4[dq].x = fmaf(p, vv.x, o4[dq].x);
                o4[dq].y = fmaf(p, vv.y, o4[dq].y);
                o4[dq].z = fmaf(p, vv.z, o4[dq].z);
                o4[dq].w = fmaf(p, vv.w, o4[dq].w);
            }
        }
        mrun = newm;
    }
    float inv = 1.f / lrun;
    float* dst = xcat + ((size_t)(b * 512 + f)) * 768 + h * 48;
#pragma unroll
    for (int i = 0; i < 12; ++i) {
        float4 o = make_float4(o4[i].x * inv, o4[i].y * inv,
                               o4[i].z * inv, o4[i].w * inv);
        *(float4*)(dst + i * 4) = o;
    }
}

// ---------------------------------------------------------------------------
// Spatial attention. One block per g = b*512+n. 192 threads = 8 heads x 24 t.
// DH viewed as (cs=2, nt=24): d = c*24 + u. Logits UNSCALED (per reference).
// Writes x_s to xcat cols [384,768): xcat[g*768 + 384 + h*48 + c*24 + t]
// ---------------------------------------------------------------------------
__global__ __launch_bounds__(192) void attn_spatial(
    const float* __restrict__ qkv, float* __restrict__ xcat)
{
    const int g = blockIdx.x;
    __shared__ float row[1152];
    for (int i = threadIdx.x; i < 288; i += 192)
        *(float4*)&row[i * 4] = *(const float4*)(qkv + (size_t)g * 1152 + i * 4);
    __syncthreads();

    const int h = threadIdx.x / 24;
    const int t = threadIdx.x % 24;
    const float* q = &row[h * 48];
    const float* k = &row[384 + h * 48];
    const float* v = &row[768 + h * 48];
    const float q0 = q[t], q1 = q[24 + t];

    float s[24];
    float mx = -3.0e38f;
#pragma unroll
    for (int u = 0; u < 24; ++u) {
        s[u] = q0 * k[u] + q1 * k[24 + u];
        mx = fmaxf(mx, s[u]);
    }
    float l = 0.f;
#pragma unroll
    for (int u = 0; u < 24; ++u) { s[u] = __expf(s[u] - mx); l += s[u]; }
    const float inv = 1.f / l;
    float o0 = 0.f, o1 = 0.f;
#pragma unroll
    for (int u = 0; u < 24; ++u) {
        o0 = fmaf(s[u], v[u], o0);
        o1 = fmaf(s[u], v[24 + u], o1);
    }
    float* dst = xcat + (size_t)g * 768 + 384 + h * 48;
    dst[t]      = o0 * inv;
    dst[24 + t] = o1 * inv;
}

// ---------------------------------------------------------------------------
// Column partial sums over frames for the gating mean.
// grid (32, 3, 8), 256 threads. partial[(b*8+part)*768 + e] = sum of 64 rows.
// ---------------------------------------------------------------------------
__global__ __launch_bounds__(256) void colsum(
    const float* __restrict__ xcat, float* __restrict__ partial)
{
    const int b = blockIdx.x, ch = blockIdx.y, part = blockIdx.z;
    const int e = ch * 256 + threadIdx.x;
    const int n0 = part * 64;
    float s = 0.f;
    for (int n = 0; n < 64; ++n)
        s += xcat[((size_t)(b * 512 + n0 + n)) * 768 + e];
    partial[((size_t)(b * 8 + part)) * 768 + e] = s;
}

// ---------------------------------------------------------------------------
// Gating: av = mean (from partials), alin = av @ Wts + bts, pairwise softmax.
// gate[b*768 + e]       = alpha_t[e]   (e in [0,384))
// gate[b*768 + 384 + e] = alpha_s[e]
// One block per batch b. 256 threads.
// ---------------------------------------------------------------------------
__global__ __launch_bounds__(256) void alpha_gate(
    const float* __restrict__ partial, const float* __restrict__ Wts,
    const float* __restrict__ bts, float* __restrict__ gate)
{
    const int b = blockIdx.x;
    __shared__ float av[768];
    __shared__ float alin[768];
    for (int i = threadIdx.x; i < 768; i += 256) {
        float s = 0.f;
#pragma unroll
        for (int p = 0; p < 8; ++p)
            s += partial[((size_t)(b * 8 + p)) * 768 + i];
        av[i] = s * (1.0f / 512.0f);
    }
    __syncthreads();
    for (int j = threadIdx.x; j < 768; j += 256) {
        float acc = bts[j];
        for (int kk = 0; kk < 768; ++kk)
            acc = fmaf(av[kk], Wts[(size_t)kk * 768 + j], acc);
        alin[j] = acc;
    }
    __syncthreads();
    for (int e = threadIdx.x; e < 384; e += 256) {
        float a0 = alin[2 * e], a1 = alin[2 * e + 1];
        float m = fmaxf(a0, a1);
        float e0 = __expf(a0 - m), e1 = __expf(a1 - m);
        float inv = 1.f / (e0 + e1);
        gate[(size_t)b * 768 + e]       = e0 * inv;
        gate[(size_t)b * 768 + 384 + e] = e1 * inv;
    }
}

// ---------------------------------------------------------------------------
// Final fused GEMM: y = (xcat * gate[b]) @ [Wfc_t; Wfc_s] + bfc_t + bfc_s
// K = 768 (first 384 rows of B come from Wfc_t, rest from Wfc_s).
// ---------------------------------------------------------------------------
__global__ __launch_bounds__(256) void gemm_final(
    const float* __restrict__ xcat, const float* __restrict__ gate,
    const float* __restrict__ Wt, const float* __restrict__ Ws,
    const float* __restrict__ bt, const float* __restrict__ bs,
    float* __restrict__ out)
{
    __shared__ float As[16][132];
    __shared__ float Bs[16][128];
    const int tid = threadIdx.x;
    const int m0 = blockIdx.x * 128;
    const int n0 = blockIdx.y * 128;
    const int tx = tid & 15;
    const int ty = tid >> 4;

    float acc[8][8];
#pragma unroll
    for (int i = 0; i < 8; ++i)
#pragma unroll
        for (int j = 0; j < 8; ++j) acc[i][j] = 0.f;

    for (int k0 = 0; k0 < 768; k0 += 16) {
        const float* W = (k0 < 384) ? Wt : Ws;
        const int kw = (k0 < 384) ? k0 : (k0 - 384);
#pragma unroll
        for (int i = 0; i < 2; ++i) {
            int idx = tid + 256 * i;
            int row = idx >> 2;
            int kq  = idx & 3;
            int m = m0 + row;
            int bIdx = m >> 9;   // /512
            float4 v = *(const float4*)(xcat + (size_t)m * 768 + k0 + kq * 4);
            float4 gv = *(const float4*)(gate + (size_t)bIdx * 768 + k0 + kq * 4);
            As[kq * 4 + 0][row] = v.x * gv.x;
            As[kq * 4 + 1][row] = v.y * gv.y;
            As[kq * 4 + 2][row] = v.z * gv.z;
            As[kq * 4 + 3][row] = v.w * gv.w;
        }
#pragma unroll
        for (int i = 0; i < 2; ++i) {
            int idx = tid + 256 * i;
            int kr = idx >> 5;
            int cq = idx & 31;
            *(float4*)&Bs[kr][cq * 4] =
                *(const float4*)(W + (size_t)(kw + kr) * 768 + n0 + cq * 4);
        }
        __syncthreads();
#pragma unroll
        for (int kk = 0; kk < 16; ++kk) {
            float a[8], b[8];
            *(float4*)&a[0] = *(const float4*)&As[kk][ty * 8];
            *(float4*)&a[4] = *(const float4*)&As[kk][ty * 8 + 4];
            *(float4*)&b[0] = *(const float4*)&Bs[kk][tx * 8];
            *(float4*)&b[4] = *(const float4*)&Bs[kk][tx * 8 + 4];
#pragma unroll
            for (int i = 0; i < 8; ++i)
#pragma unroll
                for (int j = 0; j < 8; ++j)
                    acc[i][j] = fmaf(a[i], b[j], acc[i][j]);
        }
        __syncthreads();
    }
#pragma unroll
    for (int i = 0; i < 8; ++i) {
        int m = m0 + ty * 8 + i;
#pragma unroll
        for (int j = 0; j < 8; j += 4) {
            int n = n0 + tx * 8 + j;
            float4 b1 = *(const float4*)(bt + n);
            float4 b2 = *(const float4*)(bs + n);
            float4 o;
            o.x = acc[i][j + 0] + b1.x + b2.x;
            o.y = acc[i][j + 1] + b1.y + b2.y;
            o.z = acc[i][j + 2] + b1.z + b2.z;
            o.w = acc[i][j + 3] + b1.w + b2.w;
            *(float4*)(out + (size_t)m * 768 + n) = o;
        }
    }
}

// ---------------------------------------------------------------------------
extern "C" void kernel_launch(void* const* d_in, const int* in_sizes, int n_in,
                              void* d_out, int out_size, void* d_ws, size_t ws_size,
                              hipStream_t stream)
{
    const float* x      = (const float*)d_in[0];
    const float* Wqkv_t = (const float*)d_in[1];
    const float* bqkv_t = (const float*)d_in[2];
    const float* Wqkv_s = (const float*)d_in[3];
    const float* bqkv_s = (const float*)d_in[4];
    const float* Wts    = (const float*)d_in[5];
    const float* bts    = (const float*)d_in[6];
    const float* Wfc_t  = (const float*)d_in[7];
    const float* bfc_t  = (const float*)d_in[8];
    const float* Wfc_s  = (const float*)d_in[9];
    const float* bfc_s  = (const float*)d_in[10];
    float* out = (float*)d_out;

    float* ws = (float*)d_ws;
    float* qkv     = ws;                      // 16384*1152 = 18,874,368 floats
    float* xcat    = ws + 18874368;           // 16384*768  = 12,582,912 floats
    float* partial = ws + 31457280;           // 32*8*768   =    196,608 floats
    float* gate    = ws + 31653888;           // 32*768     =     24,576 floats

    const dim3 blk256(256);

    // temporal branch
    gemm_bias<<<dim3(128, 9), blk256, 0, stream>>>(x, Wqkv_t, bqkv_t, qkv,
                                                   16384, 1152, 768);
    attn_temporal<<<dim3(2, 8, 32), blk256, 0, stream>>>(qkv, xcat);

    // spatial branch (reuses qkv scratch)
    gemm_bias<<<dim3(128, 9), blk256, 0, stream>>>(x, Wqkv_s, bqkv_s, qkv,
                                                   16384, 1152, 768);
    attn_spatial<<<dim3(16384), dim3(192), 0, stream>>>(qkv, xcat);

    // gating
    colsum<<<dim3(32, 3, 8), blk256, 0, stream>>>(xcat, partial);
    alpha_gate<<<dim3(32), blk256, 0, stream>>>(partial, Wts, bts, gate);

    // final fused gated GEMM
    gemm_final<<<dim3(128, 6), blk256, 0, stream>>>(xcat, gate, Wfc_t, Wfc_s,
                                                    bfc_t, bfc_s, out);
}

// Round 2
// 833.923 us; speedup vs baseline: 1.5256x; 1.5256x over previous
//
#include <hip/hip_runtime.h>
#include <hip/hip_bf16.h>

// B=32, N=512, H=8, DH=48, E=384, IN=768, R=16384, QKV cols=1152

typedef __attribute__((ext_vector_type(8))) short s16x8;
typedef __attribute__((ext_vector_type(4))) float f32x4;

__device__ __forceinline__ float lo2f(uint u) { return __uint_as_float(u << 16); }
__device__ __forceinline__ float hi2f(uint u) { return __uint_as_float(u & 0xffff0000u); }
__device__ __forceinline__ ushort f2bu(float f) {
    union { __hip_bfloat16 h; ushort u; } c; c.h = __float2bfloat16(f); return c.u;
}
__device__ __forceinline__ uint pk2(float a, float b) {
    return (uint)f2bu(a) | ((uint)f2bu(b) << 16);
}
__device__ __forceinline__ void gload16(const void* g, void* l) {
    __builtin_amdgcn_global_load_lds((const __attribute__((address_space(1))) void*)g,
                                     (__attribute__((address_space(3))) void*)l, 16, 0, 0);
}

// ---------------------------------------------------------------------------
// fp32 -> bf16 convert, 8 elems/thread
// ---------------------------------------------------------------------------
__global__ __launch_bounds__(256) void convert_bf16(
    const float* __restrict__ in, ushort* __restrict__ out)
{
    const int i = blockIdx.x * 256 + threadIdx.x;
    const float4* p = (const float4*)in + (size_t)i * 2;
    float4 a = p[0], b = p[1];
    uint4 o;
    o.x = pk2(a.x, a.y); o.y = pk2(a.z, a.w);
    o.z = pk2(b.x, b.y); o.w = pk2(b.z, b.w);
    ((uint4*)out)[i] = o;
}

// ---------------------------------------------------------------------------
// Transpose+convert: W fp32 [K][N] -> Bt bf16 [N][Kt] (k written at koff)
// grid (K/32, N/32), 256 threads
// ---------------------------------------------------------------------------
__global__ __launch_bounds__(256) void transpose_w(
    const float* __restrict__ W, ushort* __restrict__ Bt,
    int K, int N, int Kt, int koff)
{
    __shared__ float t[32][33];
    const int k0 = blockIdx.x * 32, n0 = blockIdx.y * 32;
    const int r = threadIdx.x >> 3, cq = threadIdx.x & 7;
    float4 v = *(const float4*)(W + (size_t)(k0 + r) * N + n0 + cq * 4);
    t[r][cq * 4 + 0] = v.x; t[r][cq * 4 + 1] = v.y;
    t[r][cq * 4 + 2] = v.z; t[r][cq * 4 + 3] = v.w;
    __syncthreads();
    ushort4 o;
    o.x = f2bu(t[cq * 4 + 0][r]); o.y = f2bu(t[cq * 4 + 1][r]);
    o.z = f2bu(t[cq * 4 + 2][r]); o.w = f2bu(t[cq * 4 + 3][r]);
    *(ushort4*)(Bt + (size_t)(n0 + r) * Kt + koff + k0 + cq * 4) = o;
}

// ---------------------------------------------------------------------------
// bf16 MFMA GEMM: C = A[M][K] @ Bt[N][K]^T + bias. 128x128 tile, BK=32,
// 256 thr = 4 waves (2x2), 16x16x32 MFMA, 4x4 frags/wave, global_load_lds.
// ---------------------------------------------------------------------------
template<int OUTBF16, int NBIAS>
__global__ __launch_bounds__(256) void gemm_mfma(
    const ushort* __restrict__ A, const ushort* __restrict__ Bt,
    const float* __restrict__ bias0, const float* __restrict__ bias1,
    void* __restrict__ Cout, int M, int N, int K)
{
    __shared__ ushort As[4096];   // [128][32]
    __shared__ ushort Bs[4096];   // [128][32]
    const int tid = threadIdx.x;
    const int m0 = blockIdx.x * 128;
    const int n0 = blockIdx.y * 128;
    const int lane = tid & 63;
    const int wr = tid >> 7;          // wave row (0..1)
    const int wc = (tid >> 6) & 1;    // wave col
    const int lr = lane & 15;
    const int kh = lane >> 4;         // 0..3 -> k offset 8*kh

    f32x4 acc[4][4];
#pragma unroll
    for (int i = 0; i < 4; ++i)
#pragma unroll
        for (int j = 0; j < 4; ++j) acc[i][j] = (f32x4){0.f, 0.f, 0.f, 0.f};

    const int arow = tid >> 2;        // 0..63
    const int kq = tid & 3;
    const ushort* gA = A + (size_t)(m0 + arow) * K + kq * 8;
    const ushort* gB = Bt + (size_t)(n0 + arow) * K + kq * 8;
    const size_t rowstep = (size_t)64 * K;
    ushort* lA0 = &As[tid * 8];
    ushort* lA1 = &As[2048 + tid * 8];
    ushort* lB0 = &Bs[tid * 8];
    ushort* lB1 = &Bs[2048 + tid * 8];
    const int aoff = (wr * 64 + lr) * 32 + kh * 8;
    const int boff = (wc * 64 + lr) * 32 + kh * 8;

    for (int k0 = 0; k0 < K; k0 += 32) {
        gload16(gA + k0, lA0);
        gload16(gA + rowstep + k0, lA1);
        gload16(gB + k0, lB0);
        gload16(gB + rowstep + k0, lB1);
        __syncthreads();
        s16x8 af[4], bfv[4];
#pragma unroll
        for (int i = 0; i < 4; ++i) af[i] = *(const s16x8*)&As[aoff + i * 512];
#pragma unroll
        for (int j = 0; j < 4; ++j) bfv[j] = *(const s16x8*)&Bs[boff + j * 512];
#pragma unroll
        for (int i = 0; i < 4; ++i)
#pragma unroll
            for (int j = 0; j < 4; ++j)
                acc[i][j] = __builtin_amdgcn_mfma_f32_16x16x32_bf16(
                    af[i], bfv[j], acc[i][j], 0, 0, 0);
        __syncthreads();
    }

    const int r0 = m0 + wr * 64 + (lane >> 4) * 4;
    const int c0 = n0 + wc * 64 + lr;
#pragma unroll
    for (int j = 0; j < 4; ++j) {
        const int col = c0 + j * 16;
        float bsum = bias0[col];
        if (NBIAS == 2) bsum += bias1[col];
#pragma unroll
        for (int i = 0; i < 4; ++i) {
            const int row = r0 + i * 16;
#pragma unroll
            for (int v = 0; v < 4; ++v) {
                const float val = acc[i][j][v] + bsum;
                if (OUTBF16)
                    ((ushort*)Cout)[(size_t)(row + v) * N + col] = f2bu(val);
                else
                    ((float*)Cout)[(size_t)(row + v) * N + col] = val;
            }
        }
    }
}

// ---------------------------------------------------------------------------
// Temporal flash attention, bf16 qkv in, bf16 xcat out (cols 0..384).
// One thread = one q row. 256 thr. grid (2, 8, 32).
// ---------------------------------------------------------------------------
__global__ __launch_bounds__(256) void attn_temporal(
    const ushort* __restrict__ qkv, ushort* __restrict__ xcat)
{
    const int b = blockIdx.z;
    const int h = blockIdx.y;
    const int f = blockIdx.x * 256 + threadIdx.x;

    __shared__ float Ks[32][48];
    __shared__ float Vs[32][48];

    const uint* qkvu = (const uint*)qkv;
    const size_t qoffu = ((size_t)(b * 512 + f)) * 576 + h * 24;
    float4 q4[12], o4[12];
#pragma unroll
    for (int t = 0; t < 6; ++t) {
        uint4 u = ((const uint4*)(qkvu + qoffu))[t];
        q4[2 * t + 0] = make_float4(lo2f(u.x), hi2f(u.x), lo2f(u.y), hi2f(u.y));
        q4[2 * t + 1] = make_float4(lo2f(u.z), hi2f(u.z), lo2f(u.w), hi2f(u.w));
    }
#pragma unroll
    for (int i = 0; i < 12; ++i) o4[i] = make_float4(0.f, 0.f, 0.f, 0.f);

    float mrun = -3.0e38f, lrun = 0.f;
    const float scale = 0.14433756729740643f; // 1/sqrt(48)

    for (int t0 = 0; t0 < 512; t0 += 32) {
        __syncthreads();
        // stage K,V: 32 rows x 24 uints each
#pragma unroll
        for (int i = 0; i < 3; ++i) {
            int idx = threadIdx.x + 256 * i;
            int row = idx / 24;
            int u = idx % 24;
            size_t src = ((size_t)(b * 512 + t0 + row)) * 576 + 192 + h * 24 + u;
            uint kw = qkvu[src];
            uint vw = qkvu[src + 192];
            Ks[row][2 * u] = lo2f(kw); Ks[row][2 * u + 1] = hi2f(kw);
            Vs[row][2 * u] = lo2f(vw); Vs[row][2 * u + 1] = hi2f(vw);
        }
        __syncthreads();

        float s[32];
#pragma unroll
        for (int j = 0; j < 32; ++j) {
            float4 acc = make_float4(0.f, 0.f, 0.f, 0.f);
#pragma unroll
            for (int dq = 0; dq < 12; ++dq) {
                float4 kv = *(const float4*)&Ks[j][dq * 4];
                acc.x = fmaf(q4[dq].x, kv.x, acc.x);
                acc.y = fmaf(q4[dq].y, kv.y, acc.y);
                acc.z = fmaf(q4[dq].z, kv.z, acc.z);
                acc.w = fmaf(q4[dq].w, kv.w, acc.w);
            }
            s[j] = (acc.x + acc.y + acc.z + acc.w) * scale;
        }
        float tmax = s[0];
#pragma unroll
        for (int j = 1; j < 32; ++j) tmax = fmaxf(tmax, s[j]);
        float newm = fmaxf(mrun, tmax);
        float corr = __expf(mrun - newm);
        lrun *= corr;
#pragma unroll
        for (int i = 0; i < 12; ++i) {
            o4[i].x *= corr; o4[i].y *= corr; o4[i].z *= corr; o4[i].w *= corr;
        }
#pragma unroll
        for (int j = 0; j < 32; ++j) {
            float p = __expf(s[j] - newm);
            lrun += p;
#pragma unroll
            for (int dq = 0; dq < 12; ++dq) {
                float4 vv = *(const float4*)&Vs[j][dq * 4];
                o4[dq].x = fmaf(p, vv.x, o4[dq].x);
                o4[dq].y = fmaf(p, vv.y, o4[dq].y);
                o4[dq].z = fmaf(p, vv.z, o4[dq].z);
                o4[dq].w = fmaf(p, vv.w, o4[dq].w);
            }
        }
        mrun = newm;
    }
    const float inv = 1.f / lrun;
    uint* dst = (uint*)xcat + ((size_t)(b * 512 + f)) * 384 + h * 24;
#pragma unroll
    for (int i = 0; i < 6; ++i) {
        uint4 o;
        o.x = pk2(o4[2 * i].x * inv, o4[2 * i].y * inv);
        o.y = pk2(o4[2 * i].z * inv, o4[2 * i].w * inv);
        o.z = pk2(o4[2 * i + 1].x * inv, o4[2 * i + 1].y * inv);
        o.w = pk2(o4[2 * i + 1].z * inv, o4[2 * i + 1].w * inv);
        ((uint4*)dst)[i] = o;
    }
}

// ---------------------------------------------------------------------------
// Spatial attention (unscaled logits). One block per g. 192 thr = 8h x 24t.
// ---------------------------------------------------------------------------
__global__ __launch_bounds__(192) void attn_spatial(
    const ushort* __restrict__ qkv, ushort* __restrict__ xcat)
{
    const int g = blockIdx.x;
    __shared__ float row[1152];
    const uint* qkvu = (const uint*)qkv;
#pragma unroll
    for (int i = 0; i < 3; ++i) {
        int idx = threadIdx.x + 192 * i;
        uint u = qkvu[(size_t)g * 576 + idx];
        row[2 * idx] = lo2f(u); row[2 * idx + 1] = hi2f(u);
    }
    __syncthreads();

    const int h = threadIdx.x / 24;
    const int t = threadIdx.x % 24;
    const float* q = &row[h * 48];
    const float* k = &row[384 + h * 48];
    const float* v = &row[768 + h * 48];
    const float q0 = q[t], q1 = q[24 + t];

    float s[24];
    float mx = -3.0e38f;
#pragma unroll
    for (int u = 0; u < 24; ++u) {
        s[u] = q0 * k[u] + q1 * k[24 + u];
        mx = fmaxf(mx, s[u]);
    }
    float l = 0.f;
#pragma unroll
    for (int u = 0; u < 24; ++u) { s[u] = __expf(s[u] - mx); l += s[u]; }
    const float inv = 1.f / l;
    float o0 = 0.f, o1 = 0.f;
#pragma unroll
    for (int u = 0; u < 24; ++u) {
        o0 = fmaf(s[u], v[u], o0);
        o1 = fmaf(s[u], v[24 + u], o1);
    }
    ushort* dst = xcat + (size_t)g * 768 + 384 + h * 48;
    dst[t] = f2bu(o0 * inv);
    dst[24 + t] = f2bu(o1 * inv);
}

// ---------------------------------------------------------------------------
// Column partial sums (bf16 in, fp32 out). grid (32,3,8).
// ---------------------------------------------------------------------------
__global__ __launch_bounds__(256) void colsum(
    const ushort* __restrict__ xcat, float* __restrict__ partial)
{
    const int b = blockIdx.x, ch = blockIdx.y, part = blockIdx.z;
    const int e = ch * 256 + threadIdx.x;
    const int n0 = part * 64;
    float s = 0.f;
    for (int n = 0; n < 64; ++n)
        s += __uint_as_float((uint)xcat[((size_t)(b * 512 + n0 + n)) * 768 + e] << 16);
    partial[((size_t)(b * 8 + part)) * 768 + e] = s;
}

// ---------------------------------------------------------------------------
// Gating. One block per batch.
// ---------------------------------------------------------------------------
__global__ __launch_bounds__(256) void alpha_gate(
    const float* __restrict__ partial, const float* __restrict__ Wts,
    const float* __restrict__ bts, float* __restrict__ gate)
{
    const int b = blockIdx.x;
    __shared__ float av[768];
    __shared__ float alin[768];
    for (int i = threadIdx.x; i < 768; i += 256) {
        float s = 0.f;
#pragma unroll
        for (int p = 0; p < 8; ++p)
            s += partial[((size_t)(b * 8 + p)) * 768 + i];
        av[i] = s * (1.0f / 512.0f);
    }
    __syncthreads();
    for (int j = threadIdx.x; j < 768; j += 256) {
        float acc = bts[j];
        for (int kk = 0; kk < 768; ++kk)
            acc = fmaf(av[kk], Wts[(size_t)kk * 768 + j], acc);
        alin[j] = acc;
    }
    __syncthreads();
    for (int e = threadIdx.x; e < 384; e += 256) {
        float a0 = alin[2 * e], a1 = alin[2 * e + 1];
        float m = fmaxf(a0, a1);
        float e0 = __expf(a0 - m), e1 = __expf(a1 - m);
        float inv = 1.f / (e0 + e1);
        gate[(size_t)b * 768 + e] = e0 * inv;
        gate[(size_t)b * 768 + 384 + e] = e1 * inv;
    }
}

// ---------------------------------------------------------------------------
// xg = bf16(xcat * gate[b]), 8 elems/thread
// ---------------------------------------------------------------------------
__global__ __launch_bounds__(256) void gate_mul(
    const ushort* __restrict__ xcat, const float* __restrict__ gate,
    ushort* __restrict__ xg)
{
    const int i = blockIdx.x * 256 + threadIdx.x;
    const int m = i / 96;
    const int k = (i % 96) * 8;
    const int b = m >> 9;
    uint4 u = ((const uint4*)xcat)[i];
    const float* g = gate + (size_t)b * 768 + k;
    float4 g0 = *(const float4*)g;
    float4 g1 = *(const float4*)(g + 4);
    uint4 o;
    o.x = pk2(lo2f(u.x) * g0.x, hi2f(u.x) * g0.y);
    o.y = pk2(lo2f(u.y) * g0.z, hi2f(u.y) * g0.w);
    o.z = pk2(lo2f(u.z) * g1.x, hi2f(u.z) * g1.y);
    o.w = pk2(lo2f(u.w) * g1.z, hi2f(u.w) * g1.w);
    ((uint4*)xg)[i] = o;
}

// ---------------------------------------------------------------------------
extern "C" void kernel_launch(void* const* d_in, const int* in_sizes, int n_in,
                              void* d_out, int out_size, void* d_ws, size_t ws_size,
                              hipStream_t stream)
{
    const float* x      = (const float*)d_in[0];
    const float* Wqkv_t = (const float*)d_in[1];
    const float* bqkv_t = (const float*)d_in[2];
    const float* Wqkv_s = (const float*)d_in[3];
    const float* bqkv_s = (const float*)d_in[4];
    const float* Wts    = (const float*)d_in[5];
    const float* bts    = (const float*)d_in[6];
    const float* Wfc_t  = (const float*)d_in[7];
    const float* bfc_t  = (const float*)d_in[8];
    const float* Wfc_s  = (const float*)d_in[9];
    const float* bfc_s  = (const float*)d_in[10];
    float* out = (float*)d_out;

    char* w = (char*)d_ws;
    ushort* qkvb   = (ushort*)(w);                 // 16384*1152 bf16 = 37,748,736 B
    ushort* xb     = (ushort*)(w + 37748736);      // 16384*768 bf16  = 25,165,824 B
    ushort* xcat   = (ushort*)(w + 62914560);      // 16384*768 bf16  = 25,165,824 B
    ushort* wbuf   = (ushort*)(w + 88080384);      // 1152*768 bf16   =  1,769,472 B
    ushort* xg     = (ushort*)(w + 89849856);      // 16384*768 bf16  = 25,165,824 B
    float*  partial= (float*)(w + 115015680);      // 32*8*768 f32    =    786,432 B
    float*  gate   = (float*)(w + 115802112);      // 32*768 f32      =     98,304 B
    // total 115,900,416 B

    const dim3 blk256(256);

    convert_bf16<<<dim3(6144), blk256, 0, stream>>>(x, xb);

    // temporal branch
    transpose_w<<<dim3(24, 36), blk256, 0, stream>>>(Wqkv_t, wbuf, 768, 1152, 768, 0);
    gemm_mfma<1, 1><<<dim3(128, 9), blk256, 0, stream>>>(
        xb, wbuf, bqkv_t, nullptr, qkvb, 16384, 1152, 768);
    attn_temporal<<<dim3(2, 8, 32), blk256, 0, stream>>>(qkvb, xcat);

    // spatial branch (reuses qkvb + wbuf)
    transpose_w<<<dim3(24, 36), blk256, 0, stream>>>(Wqkv_s, wbuf, 768, 1152, 768, 0);
    gemm_mfma<1, 1><<<dim3(128, 9), blk256, 0, stream>>>(
        xb, wbuf, bqkv_s, nullptr, qkvb, 16384, 1152, 768);
    attn_spatial<<<dim3(16384), dim3(192), 0, stream>>>(qkvb, xcat);

    // gating
    colsum<<<dim3(32, 3, 8), blk256, 0, stream>>>(xcat, partial);
    alpha_gate<<<dim3(32), blk256, 0, stream>>>(partial, Wts, bts, gate);
    gate_mul<<<dim3(6144), blk256, 0, stream>>>(xcat, gate, xg);

    // final fused GEMM: Bt = [Wfc_t; Wfc_s]^T -> [768 n][768 k]
    transpose_w<<<dim3(12, 24), blk256, 0, stream>>>(Wfc_t, wbuf, 384, 768, 768, 0);
    transpose_w<<<dim3(12, 24), blk256, 0, stream>>>(Wfc_s, wbuf, 384, 768, 768, 384);
    gemm_mfma<0, 2><<<dim3(128, 6), blk256, 0, stream>>>(
        xg, wbuf, bfc_t, bfc_s, out, 16384, 768, 768);
}

// Round 3
// 325.055 us; speedup vs baseline: 3.9139x; 2.5655x over previous
//
#include <hip/hip_runtime.h>
#include <hip/hip_bf16.h>

// B=32, N=512, H=8, DH=48, E=384, IN=768, R=16384, QKV cols=1152

typedef __attribute__((ext_vector_type(8))) short s16x8;
typedef __attribute__((ext_vector_type(4))) float f32x4;

__device__ __forceinline__ float lo2f(uint u) { return __uint_as_float(u << 16); }
__device__ __forceinline__ float hi2f(uint u) { return __uint_as_float(u & 0xffff0000u); }
__device__ __forceinline__ ushort f2bu(float f) {
    union { __hip_bfloat16 h; ushort u; } c; c.h = __float2bfloat16(f); return c.u;
}
__device__ __forceinline__ uint pk2(float a, float b) {
    return (uint)f2bu(a) | ((uint)f2bu(b) << 16);
}
__device__ __forceinline__ void gload16(const void* g, void* l) {
    __builtin_amdgcn_global_load_lds((const __attribute__((address_space(1))) void*)g,
                                     (__attribute__((address_space(3))) void*)l, 16, 0, 0);
}

// ---------------------------------------------------------------------------
// fp32 -> bf16 convert, 8 elems/thread
// ---------------------------------------------------------------------------
__global__ __launch_bounds__(256) void convert_bf16(
    const float* __restrict__ in, ushort* __restrict__ out)
{
    const int i = blockIdx.x * 256 + threadIdx.x;
    const float4* p = (const float4*)in + (size_t)i * 2;
    float4 a = p[0], b = p[1];
    uint4 o;
    o.x = pk2(a.x, a.y); o.y = pk2(a.z, a.w);
    o.z = pk2(b.x, b.y); o.w = pk2(b.z, b.w);
    ((uint4*)out)[i] = o;
}

// ---------------------------------------------------------------------------
// Transpose+convert: W fp32 [K][N] -> Bt bf16 [N][Kt] (k written at koff)
// ---------------------------------------------------------------------------
__global__ __launch_bounds__(256) void transpose_w(
    const float* __restrict__ W, ushort* __restrict__ Bt,
    int K, int N, int Kt, int koff)
{
    __shared__ float t[32][33];
    const int k0 = blockIdx.x * 32, n0 = blockIdx.y * 32;
    const int r = threadIdx.x >> 3, cq = threadIdx.x & 7;
    float4 v = *(const float4*)(W + (size_t)(k0 + r) * N + n0 + cq * 4);
    t[r][cq * 4 + 0] = v.x; t[r][cq * 4 + 1] = v.y;
    t[r][cq * 4 + 2] = v.z; t[r][cq * 4 + 3] = v.w;
    __syncthreads();
    ushort4 o;
    o.x = f2bu(t[cq * 4 + 0][r]); o.y = f2bu(t[cq * 4 + 1][r]);
    o.z = f2bu(t[cq * 4 + 2][r]); o.w = f2bu(t[cq * 4 + 3][r]);
    *(ushort4*)(Bt + (size_t)(n0 + r) * Kt + koff + k0 + cq * 4) = o;
}

// ---------------------------------------------------------------------------
// bf16 MFMA GEMM: C = A[M][K] @ Bt[N][K]^T + bias. 128x128 tile, BK=32.
// ---------------------------------------------------------------------------
template<int OUTBF16, int NBIAS>
__global__ __launch_bounds__(256) void gemm_mfma(
    const ushort* __restrict__ A, const ushort* __restrict__ Bt,
    const float* __restrict__ bias0, const float* __restrict__ bias1,
    void* __restrict__ Cout, int M, int N, int K)
{
    __shared__ ushort As[4096];
    __shared__ ushort Bs[4096];
    const int tid = threadIdx.x;
    const int m0 = blockIdx.x * 128;
    const int n0 = blockIdx.y * 128;
    const int lane = tid & 63;
    const int wr = tid >> 7;
    const int wc = (tid >> 6) & 1;
    const int lr = lane & 15;
    const int kh = lane >> 4;

    f32x4 acc[4][4];
#pragma unroll
    for (int i = 0; i < 4; ++i)
#pragma unroll
        for (int j = 0; j < 4; ++j) acc[i][j] = (f32x4){0.f, 0.f, 0.f, 0.f};

    const int arow = tid >> 2;
    const int kq = tid & 3;
    const ushort* gA = A + (size_t)(m0 + arow) * K + kq * 8;
    const ushort* gB = Bt + (size_t)(n0 + arow) * K + kq * 8;
    const size_t rowstep = (size_t)64 * K;
    ushort* lA0 = &As[tid * 8];
    ushort* lA1 = &As[2048 + tid * 8];
    ushort* lB0 = &Bs[tid * 8];
    ushort* lB1 = &Bs[2048 + tid * 8];
    const int aoff = (wr * 64 + lr) * 32 + kh * 8;
    const int boff = (wc * 64 + lr) * 32 + kh * 8;

    for (int k0 = 0; k0 < K; k0 += 32) {
        gload16(gA + k0, lA0);
        gload16(gA + rowstep + k0, lA1);
        gload16(gB + k0, lB0);
        gload16(gB + rowstep + k0, lB1);
        __syncthreads();
        s16x8 af[4], bfv[4];
#pragma unroll
        for (int i = 0; i < 4; ++i) af[i] = *(const s16x8*)&As[aoff + i * 512];
#pragma unroll
        for (int j = 0; j < 4; ++j) bfv[j] = *(const s16x8*)&Bs[boff + j * 512];
#pragma unroll
        for (int i = 0; i < 4; ++i)
#pragma unroll
            for (int j = 0; j < 4; ++j)
                acc[i][j] = __builtin_amdgcn_mfma_f32_16x16x32_bf16(
                    af[i], bfv[j], acc[i][j], 0, 0, 0);
        __syncthreads();
    }

    const int r0 = m0 + wr * 64 + (lane >> 4) * 4;
    const int c0 = n0 + wc * 64 + lr;
#pragma unroll
    for (int j = 0; j < 4; ++j) {
        const int col = c0 + j * 16;
        float bsum = bias0[col];
        if (NBIAS == 2) bsum += bias1[col];
#pragma unroll
        for (int i = 0; i < 4; ++i) {
            const int row = r0 + i * 16;
#pragma unroll
            for (int v = 0; v < 4; ++v) {
                const float val = acc[i][j][v] + bsum;
                if (OUTBF16)
                    ((ushort*)Cout)[(size_t)(row + v) * N + col] = f2bu(val);
                else
                    ((float*)Cout)[(size_t)(row + v) * N + col] = val;
            }
        }
    }
}

// ---------------------------------------------------------------------------
// Temporal flash attention, MFMA version.
// Grid (4 qtiles, 8 h, 32 b), 256 thr = 4 waves. Wave owns 32 q rows.
// Swapped QK^T: S^T = mfma(K_frag, Q_frag) -> kv reduction is lane-local+shfl.
// K staged [64][72] (d padded 48->64 with zeros), V staged transposed [48][72],
// P round-trips through per-wave LDS [32][72] as bf16.
// ---------------------------------------------------------------------------
__global__ __launch_bounds__(256) void attn_temporal(
    const ushort* __restrict__ qkv, ushort* __restrict__ xcat)
{
    const int qt = blockIdx.x, h = blockIdx.y, b = blockIdx.z;
    const int tid = threadIdx.x;
    const int w = tid >> 6;
    const int lane = tid & 63;
    const int lr = lane & 15;
    const int g = lane >> 4;

    __shared__ ushort Ks[64 * 72];      // [kv][72], cols 48..63 zero
    __shared__ ushort Vt[48 * 72];      // [d][72], col = kv
    __shared__ ushort Pl[4][32 * 72];   // per wave: [q][72], col = kv
    __shared__ float statsL[4][32];

    // zero-fill Ks cols 48..63 (once; staging never touches them)
    {
        int r = tid >> 2, c = 48 + (tid & 3) * 4;
        *(uint2*)&Ks[r * 72 + c] = make_uint2(0u, 0u);
    }

    const uint* qkvu = (const uint*)qkv;
    const int qrow0 = qt * 128 + w * 32;

    // Q B-frags straight from global: q row = qrow0+16n+lr, d = 8g(+32ks)
    s16x8 qf[2][2];
#pragma unroll
    for (int n = 0; n < 2; ++n) {
        const size_t rb = (size_t)(b * 512 + qrow0 + 16 * n + lr) * 1152 + h * 48 + 8 * g;
        qf[n][0] = *(const s16x8*)(qkv + rb);
        qf[n][1] = (g < 2) ? *(const s16x8*)(qkv + rb + 32)
                           : (s16x8){0, 0, 0, 0, 0, 0, 0, 0};
    }

    f32x4 o[2][3];
#pragma unroll
    for (int mq = 0; mq < 2; ++mq)
#pragma unroll
        for (int nd = 0; nd < 3; ++nd) o[mq][nd] = (f32x4){0.f, 0.f, 0.f, 0.f};
    float mrun[2] = {-3.0e38f, -3.0e38f};
    float lsum[2] = {0.f, 0.f};
    const float scale = 0.14433756729740643f; // 1/sqrt(48)

    for (int kv0 = 0; kv0 < 512; kv0 += 64) {
        // ---- stage K [kv][d] and V^T [d][kv] ----
#pragma unroll
        for (int i = 0; i < 6; ++i) {
            int idx = tid + 256 * i;
            int row = idx / 24;
            int du = idx % 24;
            const uint* src = qkvu + (size_t)(b * 512 + kv0 + row) * 576 + h * 24 + du;
            uint kwd = src[192];
            uint vwd = src[384];
            *(uint*)&Ks[row * 72 + 2 * du] = kwd;
            Vt[(2 * du) * 72 + row] = (ushort)(vwd & 0xffffu);
            Vt[(2 * du + 1) * 72 + row] = (ushort)(vwd >> 16);
        }
        __syncthreads();

        // ---- QK^T (swapped): sa[m][n] = S^T tile, kv=16m+4g+v, q=16n+lr ----
        f32x4 sa[4][2];
#pragma unroll
        for (int m = 0; m < 4; ++m)
#pragma unroll
            for (int n = 0; n < 2; ++n) sa[m][n] = (f32x4){0.f, 0.f, 0.f, 0.f};
#pragma unroll
        for (int ks = 0; ks < 2; ++ks)
#pragma unroll
            for (int m = 0; m < 4; ++m) {
                s16x8 kf = *(const s16x8*)&Ks[(16 * m + lr) * 72 + 8 * g + 32 * ks];
#pragma unroll
                for (int n = 0; n < 2; ++n)
                    sa[m][n] = __builtin_amdgcn_mfma_f32_16x16x32_bf16(
                        kf, qf[n][ks], sa[m][n], 0, 0, 0);
            }

        // ---- online softmax; write P (bf16) to per-wave LDS ----
#pragma unroll
        for (int n = 0; n < 2; ++n) {
            float tmax = -3.0e38f;
#pragma unroll
            for (int m = 0; m < 4; ++m)
#pragma unroll
                for (int v = 0; v < 4; ++v) tmax = fmaxf(tmax, sa[m][n][v]);
            tmax = fmaxf(tmax, __shfl_xor(tmax, 16));
            tmax = fmaxf(tmax, __shfl_xor(tmax, 32));
            float mnew = fmaxf(mrun[n], tmax * scale);
            float corr = __expf(mrun[n] - mnew);
            mrun[n] = mnew;
            float psum = 0.f;
#pragma unroll
            for (int m = 0; m < 4; ++m) {
                float p0 = __expf(fmaf(sa[m][n][0], scale, -mnew));
                float p1 = __expf(fmaf(sa[m][n][1], scale, -mnew));
                float p2 = __expf(fmaf(sa[m][n][2], scale, -mnew));
                float p3 = __expf(fmaf(sa[m][n][3], scale, -mnew));
                psum += (p0 + p1) + (p2 + p3);
                const int base = (16 * n + lr) * 72 + 16 * m + 4 * g;
                *(uint*)&Pl[w][base] = pk2(p0, p1);
                *(uint*)&Pl[w][base + 2] = pk2(p2, p3);
            }
            psum += __shfl_xor(psum, 16);
            psum += __shfl_xor(psum, 32);
            lsum[n] = lsum[n] * corr + psum;
            if (g == 0) statsL[w][16 * n + lr] = corr;
        }

        // ---- rescale O by per-q corr (row-indexed lanes) ----
        f32x4 corr4[2];
#pragma unroll
        for (int mq = 0; mq < 2; ++mq)
            corr4[mq] = *(const f32x4*)&statsL[w][16 * mq + 4 * g];
#pragma unroll
        for (int mq = 0; mq < 2; ++mq)
#pragma unroll
            for (int nd = 0; nd < 3; ++nd)
#pragma unroll
                for (int v = 0; v < 4; ++v) o[mq][nd][v] *= corr4[mq][v];

        // ---- PV: o[mq][nd] += P[q][kv] @ V[kv][d] ----
#pragma unroll
        for (int ks = 0; ks < 2; ++ks) {
            s16x8 vf[3];
#pragma unroll
            for (int nd = 0; nd < 3; ++nd)
                vf[nd] = *(const s16x8*)&Vt[(16 * nd + lr) * 72 + 8 * g + 32 * ks];
#pragma unroll
            for (int mq = 0; mq < 2; ++mq) {
                s16x8 pf = *(const s16x8*)&Pl[w][(16 * mq + lr) * 72 + 8 * g + 32 * ks];
#pragma unroll
                for (int nd = 0; nd < 3; ++nd)
                    o[mq][nd] = __builtin_amdgcn_mfma_f32_16x16x32_bf16(
                        pf, vf[nd], o[mq][nd], 0, 0, 0);
            }
        }
        __syncthreads();
    }

    // ---- finalize: redistribute lsum to row-indexed lanes, write out ----
    if (g == 0) { statsL[w][lr] = lsum[0]; statsL[w][16 + lr] = lsum[1]; }
    f32x4 linv[2];
#pragma unroll
    for (int mq = 0; mq < 2; ++mq) {
        f32x4 lv = *(const f32x4*)&statsL[w][16 * mq + 4 * g];
#pragma unroll
        for (int v = 0; v < 4; ++v) linv[mq][v] = 1.f / lv[v];
    }
#pragma unroll
    for (int mq = 0; mq < 2; ++mq)
#pragma unroll
        for (int v = 0; v < 4; ++v) {
            const int qrow = qrow0 + 16 * mq + 4 * g + v;
            ushort* dst = xcat + (size_t)(b * 512 + qrow) * 768 + h * 48;
#pragma unroll
            for (int nd = 0; nd < 3; ++nd)
                dst[16 * nd + lr] = f2bu(o[mq][nd][v] * linv[mq][v]);
        }
}

// ---------------------------------------------------------------------------
// Spatial attention (unscaled logits). One block per g. 192 thr = 8h x 24t.
// ---------------------------------------------------------------------------
__global__ __launch_bounds__(192) void attn_spatial(
    const ushort* __restrict__ qkv, ushort* __restrict__ xcat)
{
    const int g = blockIdx.x;
    __shared__ float row[1152];
    const uint* qkvu = (const uint*)qkv;
#pragma unroll
    for (int i = 0; i < 3; ++i) {
        int idx = threadIdx.x + 192 * i;
        uint u = qkvu[(size_t)g * 576 + idx];
        row[2 * idx] = lo2f(u); row[2 * idx + 1] = hi2f(u);
    }
    __syncthreads();

    const int h = threadIdx.x / 24;
    const int t = threadIdx.x % 24;
    const float* q = &row[h * 48];
    const float* k = &row[384 + h * 48];
    const float* v = &row[768 + h * 48];
    const float q0 = q[t], q1 = q[24 + t];

    float s[24];
    float mx = -3.0e38f;
#pragma unroll
    for (int u = 0; u < 24; ++u) {
        s[u] = q0 * k[u] + q1 * k[24 + u];
        mx = fmaxf(mx, s[u]);
    }
    float l = 0.f;
#pragma unroll
    for (int u = 0; u < 24; ++u) { s[u] = __expf(s[u] - mx); l += s[u]; }
    const float inv = 1.f / l;
    float o0 = 0.f, o1 = 0.f;
#pragma unroll
    for (int u = 0; u < 24; ++u) {
        o0 = fmaf(s[u], v[u], o0);
        o1 = fmaf(s[u], v[24 + u], o1);
    }
    ushort* dst = xcat + (size_t)g * 768 + 384 + h * 48;
    dst[t] = f2bu(o0 * inv);
    dst[24 + t] = f2bu(o1 * inv);
}

// ---------------------------------------------------------------------------
// Column partial sums (bf16 in, fp32 out). grid (32,3,8).
// ---------------------------------------------------------------------------
__global__ __launch_bounds__(256) void colsum(
    const ushort* __restrict__ xcat, float* __restrict__ partial)
{
    const int b = blockIdx.x, ch = blockIdx.y, part = blockIdx.z;
    const int e = ch * 256 + threadIdx.x;
    const int n0 = part * 64;
    float s = 0.f;
    for (int n = 0; n < 64; ++n)
        s += __uint_as_float((uint)xcat[((size_t)(b * 512 + n0 + n)) * 768 + e] << 16);
    partial[((size_t)(b * 8 + part)) * 768 + e] = s;
}

// ---------------------------------------------------------------------------
// Gating. One block per batch.
// ---------------------------------------------------------------------------
__global__ __launch_bounds__(256) void alpha_gate(
    const float* __restrict__ partial, const float* __restrict__ Wts,
    const float* __restrict__ bts, float* __restrict__ gate)
{
    const int b = blockIdx.x;
    __shared__ float av[768];
    __shared__ float alin[768];
    for (int i = threadIdx.x; i < 768; i += 256) {
        float s = 0.f;
#pragma unroll
        for (int p = 0; p < 8; ++p)
            s += partial[((size_t)(b * 8 + p)) * 768 + i];
        av[i] = s * (1.0f / 512.0f);
    }
    __syncthreads();
    for (int j = threadIdx.x; j < 768; j += 256) {
        float acc = bts[j];
        for (int kk = 0; kk < 768; ++kk)
            acc = fmaf(av[kk], Wts[(size_t)kk * 768 + j], acc);
        alin[j] = acc;
    }
    __syncthreads();
    for (int e = threadIdx.x; e < 384; e += 256) {
        float a0 = alin[2 * e], a1 = alin[2 * e + 1];
        float m = fmaxf(a0, a1);
        float e0 = __expf(a0 - m), e1 = __expf(a1 - m);
        float inv = 1.f / (e0 + e1);
        gate[(size_t)b * 768 + e] = e0 * inv;
        gate[(size_t)b * 768 + 384 + e] = e1 * inv;
    }
}

// ---------------------------------------------------------------------------
// xg = bf16(xcat * gate[b]), 8 elems/thread
// ---------------------------------------------------------------------------
__global__ __launch_bounds__(256) void gate_mul(
    const ushort* __restrict__ xcat, const float* __restrict__ gate,
    ushort* __restrict__ xg)
{
    const int i = blockIdx.x * 256 + threadIdx.x;
    const int m = i / 96;
    const int k = (i % 96) * 8;
    const int b = m >> 9;
    uint4 u = ((const uint4*)xcat)[i];
    const float* g = gate + (size_t)b * 768 + k;
    float4 g0 = *(const float4*)g;
    float4 g1 = *(const float4*)(g + 4);
    uint4 o;
    o.x = pk2(lo2f(u.x) * g0.x, hi2f(u.x) * g0.y);
    o.y = pk2(lo2f(u.y) * g0.z, hi2f(u.y) * g0.w);
    o.z = pk2(lo2f(u.z) * g1.x, hi2f(u.z) * g1.y);
    o.w = pk2(lo2f(u.w) * g1.z, hi2f(u.w) * g1.w);
    ((uint4*)xg)[i] = o;
}

// ---------------------------------------------------------------------------
extern "C" void kernel_launch(void* const* d_in, const int* in_sizes, int n_in,
                              void* d_out, int out_size, void* d_ws, size_t ws_size,
                              hipStream_t stream)
{
    const float* x      = (const float*)d_in[0];
    const float* Wqkv_t = (const float*)d_in[1];
    const float* bqkv_t = (const float*)d_in[2];
    const float* Wqkv_s = (const float*)d_in[3];
    const float* bqkv_s = (const float*)d_in[4];
    const float* Wts    = (const float*)d_in[5];
    const float* bts    = (const float*)d_in[6];
    const float* Wfc_t  = (const float*)d_in[7];
    const float* bfc_t  = (const float*)d_in[8];
    const float* Wfc_s  = (const float*)d_in[9];
    const float* bfc_s  = (const float*)d_in[10];
    float* out = (float*)d_out;

    char* w = (char*)d_ws;
    ushort* qkvb   = (ushort*)(w);                 // 16384*1152 bf16
    ushort* xb     = (ushort*)(w + 37748736);      // 16384*768 bf16
    ushort* xcat   = (ushort*)(w + 62914560);      // 16384*768 bf16
    ushort* wbuf   = (ushort*)(w + 88080384);      // 1152*768 bf16
    ushort* xg     = (ushort*)(w + 89849856);      // 16384*768 bf16
    float*  partial= (float*)(w + 115015680);      // 32*8*768 f32
    float*  gate   = (float*)(w + 115802112);      // 32*768 f32

    const dim3 blk256(256);

    convert_bf16<<<dim3(6144), blk256, 0, stream>>>(x, xb);

    // temporal branch
    transpose_w<<<dim3(24, 36), blk256, 0, stream>>>(Wqkv_t, wbuf, 768, 1152, 768, 0);
    gemm_mfma<1, 1><<<dim3(128, 9), blk256, 0, stream>>>(
        xb, wbuf, bqkv_t, nullptr, qkvb, 16384, 1152, 768);
    attn_temporal<<<dim3(4, 8, 32), blk256, 0, stream>>>(qkvb, xcat);

    // spatial branch (reuses qkvb + wbuf)
    transpose_w<<<dim3(24, 36), blk256, 0, stream>>>(Wqkv_s, wbuf, 768, 1152, 768, 0);
    gemm_mfma<1, 1><<<dim3(128, 9), blk256, 0, stream>>>(
        xb, wbuf, bqkv_s, nullptr, qkvb, 16384, 1152, 768);
    attn_spatial<<<dim3(16384), dim3(192), 0, stream>>>(qkvb, xcat);

    // gating
    colsum<<<dim3(32, 3, 8), blk256, 0, stream>>>(xcat, partial);
    alpha_gate<<<dim3(32), blk256, 0, stream>>>(partial, Wts, bts, gate);
    gate_mul<<<dim3(6144), blk256, 0, stream>>>(xcat, gate, xg);

    // final fused GEMM: Bt = [Wfc_t; Wfc_s]^T -> [768 n][768 k]
    transpose_w<<<dim3(12, 24), blk256, 0, stream>>>(Wfc_t, wbuf, 384, 768, 768, 0);
    transpose_w<<<dim3(12, 24), blk256, 0, stream>>>(Wfc_s, wbuf, 384, 768, 768, 384);
    gemm_mfma<0, 2><<<dim3(128, 6), blk256, 0, stream>>>(
        xg, wbuf, bfc_t, bfc_s, out, 16384, 768, 768);
}

// Round 4
// 271.414 us; speedup vs baseline: 4.6875x; 1.1976x over previous
//
#include <hip/hip_runtime.h>
#include <hip/hip_bf16.h>

// B=32, N=512, H=8, DH=48, E=384, IN=768, R=16384, QKV cols=1152

typedef __attribute__((ext_vector_type(8))) short s16x8;
typedef __attribute__((ext_vector_type(4))) float f32x4;

__device__ __forceinline__ float lo2f(uint u) { return __uint_as_float(u << 16); }
__device__ __forceinline__ float hi2f(uint u) { return __uint_as_float(u & 0xffff0000u); }
__device__ __forceinline__ ushort f2bu(float f) {
    union { __hip_bfloat16 h; ushort u; } c; c.h = __float2bfloat16(f); return c.u;
}
__device__ __forceinline__ uint pk2(float a, float b) {
    return (uint)f2bu(a) | ((uint)f2bu(b) << 16);
}
__device__ __forceinline__ void gload16(const void* g, void* l) {
    __builtin_amdgcn_global_load_lds((const __attribute__((address_space(1))) void*)g,
                                     (__attribute__((address_space(3))) void*)l, 16, 0, 0);
}

// ---------------------------------------------------------------------------
// fp32 -> bf16 convert, 8 elems/thread
// ---------------------------------------------------------------------------
__global__ __launch_bounds__(256) void convert_bf16(
    const float* __restrict__ in, ushort* __restrict__ out)
{
    const int i = blockIdx.x * 256 + threadIdx.x;
    const float4* p = (const float4*)in + (size_t)i * 2;
    float4 a = p[0], b = p[1];
    uint4 o;
    o.x = pk2(a.x, a.y); o.y = pk2(a.z, a.w);
    o.z = pk2(b.x, b.y); o.w = pk2(b.z, b.w);
    ((uint4*)out)[i] = o;
}

// ---------------------------------------------------------------------------
// Transpose+convert: W fp32 [K][N] -> Bt bf16 [N][Kt] (k written at koff)
// ---------------------------------------------------------------------------
__global__ __launch_bounds__(256) void transpose_w(
    const float* __restrict__ W, ushort* __restrict__ Bt,
    int K, int N, int Kt, int koff)
{
    __shared__ float t[32][33];
    const int k0 = blockIdx.x * 32, n0 = blockIdx.y * 32;
    const int r = threadIdx.x >> 3, cq = threadIdx.x & 7;
    float4 v = *(const float4*)(W + (size_t)(k0 + r) * N + n0 + cq * 4);
    t[r][cq * 4 + 0] = v.x; t[r][cq * 4 + 1] = v.y;
    t[r][cq * 4 + 2] = v.z; t[r][cq * 4 + 3] = v.w;
    __syncthreads();
    ushort4 o;
    o.x = f2bu(t[cq * 4 + 0][r]); o.y = f2bu(t[cq * 4 + 1][r]);
    o.z = f2bu(t[cq * 4 + 2][r]); o.w = f2bu(t[cq * 4 + 3][r]);
    *(ushort4*)(Bt + (size_t)(n0 + r) * Kt + koff + k0 + cq * 4) = o;
}

// ---------------------------------------------------------------------------
// bf16 MFMA GEMM: C = A[M][K] @ Bt[N][K]^T + bias. 128x128 tile, BK=32.
// ---------------------------------------------------------------------------
template<int OUTBF16, int NBIAS>
__global__ __launch_bounds__(256) void gemm_mfma(
    const ushort* __restrict__ A, const ushort* __restrict__ Bt,
    const float* __restrict__ bias0, const float* __restrict__ bias1,
    void* __restrict__ Cout, int M, int N, int K)
{
    __shared__ ushort As[4096];
    __shared__ ushort Bs[4096];
    const int tid = threadIdx.x;
    const int m0 = blockIdx.x * 128;
    const int n0 = blockIdx.y * 128;
    const int lane = tid & 63;
    const int wr = tid >> 7;
    const int wc = (tid >> 6) & 1;
    const int lr = lane & 15;
    const int kh = lane >> 4;

    f32x4 acc[4][4];
#pragma unroll
    for (int i = 0; i < 4; ++i)
#pragma unroll
        for (int j = 0; j < 4; ++j) acc[i][j] = (f32x4){0.f, 0.f, 0.f, 0.f};

    const int arow = tid >> 2;
    const int kq = tid & 3;
    const ushort* gA = A + (size_t)(m0 + arow) * K + kq * 8;
    const ushort* gB = Bt + (size_t)(n0 + arow) * K + kq * 8;
    const size_t rowstep = (size_t)64 * K;
    ushort* lA0 = &As[tid * 8];
    ushort* lA1 = &As[2048 + tid * 8];
    ushort* lB0 = &Bs[tid * 8];
    ushort* lB1 = &Bs[2048 + tid * 8];
    const int aoff = (wr * 64 + lr) * 32 + kh * 8;
    const int boff = (wc * 64 + lr) * 32 + kh * 8;

    for (int k0 = 0; k0 < K; k0 += 32) {
        gload16(gA + k0, lA0);
        gload16(gA + rowstep + k0, lA1);
        gload16(gB + k0, lB0);
        gload16(gB + rowstep + k0, lB1);
        __syncthreads();
        s16x8 af[4], bfv[4];
#pragma unroll
        for (int i = 0; i < 4; ++i) af[i] = *(const s16x8*)&As[aoff + i * 512];
#pragma unroll
        for (int j = 0; j < 4; ++j) bfv[j] = *(const s16x8*)&Bs[boff + j * 512];
#pragma unroll
        for (int i = 0; i < 4; ++i)
#pragma unroll
            for (int j = 0; j < 4; ++j)
                acc[i][j] = __builtin_amdgcn_mfma_f32_16x16x32_bf16(
                    af[i], bfv[j], acc[i][j], 0, 0, 0);
        __syncthreads();
    }

    const int r0 = m0 + wr * 64 + (lane >> 4) * 4;
    const int c0 = n0 + wc * 64 + lr;
#pragma unroll
    for (int j = 0; j < 4; ++j) {
        const int col = c0 + j * 16;
        float bsum = bias0[col];
        if (NBIAS == 2) bsum += bias1[col];
#pragma unroll
        for (int i = 0; i < 4; ++i) {
            const int row = r0 + i * 16;
#pragma unroll
            for (int v = 0; v < 4; ++v) {
                const float val = acc[i][j][v] + bsum;
                if (OUTBF16)
                    ((ushort*)Cout)[(size_t)(row + v) * N + col] = f2bu(val);
                else
                    ((float*)Cout)[(size_t)(row + v) * N + col] = val;
            }
        }
    }
}

// ---------------------------------------------------------------------------
// Temporal flash attention, MFMA version. Grid (4,8,32), 256 thr = 4 waves.
// ---------------------------------------------------------------------------
__global__ __launch_bounds__(256) void attn_temporal(
    const ushort* __restrict__ qkv, ushort* __restrict__ xcat)
{
    const int qt = blockIdx.x, h = blockIdx.y, b = blockIdx.z;
    const int tid = threadIdx.x;
    const int w = tid >> 6;
    const int lane = tid & 63;
    const int lr = lane & 15;
    const int g = lane >> 4;

    __shared__ ushort Ks[64 * 72];      // [kv][72], cols 48..63 zero
    __shared__ ushort Vt[48 * 72];      // [d][72], col = kv
    __shared__ ushort Pl[4][32 * 72];   // per wave: [q][72], col = kv
    __shared__ float statsL[4][32];

    {
        int r = tid >> 2, c = 48 + (tid & 3) * 4;
        *(uint2*)&Ks[r * 72 + c] = make_uint2(0u, 0u);
    }

    const uint* qkvu = (const uint*)qkv;
    const int qrow0 = qt * 128 + w * 32;

    s16x8 qf[2][2];
#pragma unroll
    for (int n = 0; n < 2; ++n) {
        const size_t rb = (size_t)(b * 512 + qrow0 + 16 * n + lr) * 1152 + h * 48 + 8 * g;
        qf[n][0] = *(const s16x8*)(qkv + rb);
        qf[n][1] = (g < 2) ? *(const s16x8*)(qkv + rb + 32)
                           : (s16x8){0, 0, 0, 0, 0, 0, 0, 0};
    }

    f32x4 o[2][3];
#pragma unroll
    for (int mq = 0; mq < 2; ++mq)
#pragma unroll
        for (int nd = 0; nd < 3; ++nd) o[mq][nd] = (f32x4){0.f, 0.f, 0.f, 0.f};
    float mrun[2] = {-3.0e38f, -3.0e38f};
    float lsum[2] = {0.f, 0.f};
    const float scale = 0.14433756729740643f; // 1/sqrt(48)

    for (int kv0 = 0; kv0 < 512; kv0 += 64) {
#pragma unroll
        for (int i = 0; i < 6; ++i) {
            int idx = tid + 256 * i;
            int row = idx / 24;
            int du = idx % 24;
            const uint* src = qkvu + (size_t)(b * 512 + kv0 + row) * 576 + h * 24 + du;
            uint kwd = src[192];
            uint vwd = src[384];
            *(uint*)&Ks[row * 72 + 2 * du] = kwd;
            Vt[(2 * du) * 72 + row] = (ushort)(vwd & 0xffffu);
            Vt[(2 * du + 1) * 72 + row] = (ushort)(vwd >> 16);
        }
        __syncthreads();

        f32x4 sa[4][2];
#pragma unroll
        for (int m = 0; m < 4; ++m)
#pragma unroll
            for (int n = 0; n < 2; ++n) sa[m][n] = (f32x4){0.f, 0.f, 0.f, 0.f};
#pragma unroll
        for (int ks = 0; ks < 2; ++ks)
#pragma unroll
            for (int m = 0; m < 4; ++m) {
                s16x8 kf = *(const s16x8*)&Ks[(16 * m + lr) * 72 + 8 * g + 32 * ks];
#pragma unroll
                for (int n = 0; n < 2; ++n)
                    sa[m][n] = __builtin_amdgcn_mfma_f32_16x16x32_bf16(
                        kf, qf[n][ks], sa[m][n], 0, 0, 0);
            }

#pragma unroll
        for (int n = 0; n < 2; ++n) {
            float tmax = -3.0e38f;
#pragma unroll
            for (int m = 0; m < 4; ++m)
#pragma unroll
                for (int v = 0; v < 4; ++v) tmax = fmaxf(tmax, sa[m][n][v]);
            tmax = fmaxf(tmax, __shfl_xor(tmax, 16));
            tmax = fmaxf(tmax, __shfl_xor(tmax, 32));
            float mnew = fmaxf(mrun[n], tmax * scale);
            float corr = __expf(mrun[n] - mnew);
            mrun[n] = mnew;
            float psum = 0.f;
#pragma unroll
            for (int m = 0; m < 4; ++m) {
                float p0 = __expf(fmaf(sa[m][n][0], scale, -mnew));
                float p1 = __expf(fmaf(sa[m][n][1], scale, -mnew));
                float p2 = __expf(fmaf(sa[m][n][2], scale, -mnew));
                float p3 = __expf(fmaf(sa[m][n][3], scale, -mnew));
                psum += (p0 + p1) + (p2 + p3);
                const int base = (16 * n + lr) * 72 + 16 * m + 4 * g;
                *(uint*)&Pl[w][base] = pk2(p0, p1);
                *(uint*)&Pl[w][base + 2] = pk2(p2, p3);
            }
            psum += __shfl_xor(psum, 16);
            psum += __shfl_xor(psum, 32);
            lsum[n] = lsum[n] * corr + psum;
            if (g == 0) statsL[w][16 * n + lr] = corr;
        }

        f32x4 corr4[2];
#pragma unroll
        for (int mq = 0; mq < 2; ++mq)
            corr4[mq] = *(const f32x4*)&statsL[w][16 * mq + 4 * g];
#pragma unroll
        for (int mq = 0; mq < 2; ++mq)
#pragma unroll
            for (int nd = 0; nd < 3; ++nd)
#pragma unroll
                for (int v = 0; v < 4; ++v) o[mq][nd][v] *= corr4[mq][v];

#pragma unroll
        for (int ks = 0; ks < 2; ++ks) {
            s16x8 vf[3];
#pragma unroll
            for (int nd = 0; nd < 3; ++nd)
                vf[nd] = *(const s16x8*)&Vt[(16 * nd + lr) * 72 + 8 * g + 32 * ks];
#pragma unroll
            for (int mq = 0; mq < 2; ++mq) {
                s16x8 pf = *(const s16x8*)&Pl[w][(16 * mq + lr) * 72 + 8 * g + 32 * ks];
#pragma unroll
                for (int nd = 0; nd < 3; ++nd)
                    o[mq][nd] = __builtin_amdgcn_mfma_f32_16x16x32_bf16(
                        pf, vf[nd], o[mq][nd], 0, 0, 0);
            }
        }
        __syncthreads();
    }

    if (g == 0) { statsL[w][lr] = lsum[0]; statsL[w][16 + lr] = lsum[1]; }
    f32x4 linv[2];
#pragma unroll
    for (int mq = 0; mq < 2; ++mq) {
        f32x4 lv = *(const f32x4*)&statsL[w][16 * mq + 4 * g];
#pragma unroll
        for (int v = 0; v < 4; ++v) linv[mq][v] = 1.f / lv[v];
    }
#pragma unroll
    for (int mq = 0; mq < 2; ++mq)
#pragma unroll
        for (int v = 0; v < 4; ++v) {
            const int qrow = qrow0 + 16 * mq + 4 * g + v;
            ushort* dst = xcat + (size_t)(b * 512 + qrow) * 768 + h * 48;
#pragma unroll
            for (int nd = 0; nd < 3; ++nd)
                dst[16 * nd + lr] = f2bu(o[mq][nd][v] * linv[mq][v]);
        }
}

// ---------------------------------------------------------------------------
// Spatial attention (unscaled logits). One block per g. 192 thr = 8h x 24t.
// ---------------------------------------------------------------------------
__global__ __launch_bounds__(192) void attn_spatial(
    const ushort* __restrict__ qkv, ushort* __restrict__ xcat)
{
    const int g = blockIdx.x;
    __shared__ float row[1152];
    const uint* qkvu = (const uint*)qkv;
#pragma unroll
    for (int i = 0; i < 3; ++i) {
        int idx = threadIdx.x + 192 * i;
        uint u = qkvu[(size_t)g * 576 + idx];
        row[2 * idx] = lo2f(u); row[2 * idx + 1] = hi2f(u);
    }
    __syncthreads();

    const int h = threadIdx.x / 24;
    const int t = threadIdx.x % 24;
    const float* q = &row[h * 48];
    const float* k = &row[384 + h * 48];
    const float* v = &row[768 + h * 48];
    const float q0 = q[t], q1 = q[24 + t];

    float s[24];
    float mx = -3.0e38f;
#pragma unroll
    for (int u = 0; u < 24; ++u) {
        s[u] = q0 * k[u] + q1 * k[24 + u];
        mx = fmaxf(mx, s[u]);
    }
    float l = 0.f;
#pragma unroll
    for (int u = 0; u < 24; ++u) { s[u] = __expf(s[u] - mx); l += s[u]; }
    const float inv = 1.f / l;
    float o0 = 0.f, o1 = 0.f;
#pragma unroll
    for (int u = 0; u < 24; ++u) {
        o0 = fmaf(s[u], v[u], o0);
        o1 = fmaf(s[u], v[24 + u], o1);
    }
    ushort* dst = xcat + (size_t)g * 768 + 384 + h * 48;
    dst[t] = f2bu(o0 * inv);
    dst[24 + t] = f2bu(o1 * inv);
}

// ---------------------------------------------------------------------------
// Column partial sums (bf16 in, fp32 out). grid (32,3,8).
// ---------------------------------------------------------------------------
__global__ __launch_bounds__(256) void colsum(
    const ushort* __restrict__ xcat, float* __restrict__ partial)
{
    const int b = blockIdx.x, ch = blockIdx.y, part = blockIdx.z;
    const int e = ch * 256 + threadIdx.x;
    const int n0 = part * 64;
    float s = 0.f;
    for (int n = 0; n < 64; ++n)
        s += __uint_as_float((uint)xcat[((size_t)(b * 512 + n0 + n)) * 768 + e] << 16);
    partial[((size_t)(b * 8 + part)) * 768 + e] = s;
}

// ---------------------------------------------------------------------------
// Gating, parallel version. grid (32 b, 6 j-tiles of 128), 256 thr.
// thread = (j in tile: tid&127, k-segment: tid>>7). 8-way unrolled k loop.
// ---------------------------------------------------------------------------
__global__ __launch_bounds__(256) void alpha_gate(
    const float* __restrict__ partial, const float* __restrict__ Wts,
    const float* __restrict__ bts, float* __restrict__ gate)
{
    const int b = blockIdx.x;
    const int j0 = blockIdx.y * 128;
    __shared__ float av[768];
    __shared__ float psum[2][128];

    // av = mean over frames (from 8 partials)
    for (int i = threadIdx.x; i < 768; i += 256) {
        float s = 0.f;
#pragma unroll
        for (int p = 0; p < 8; ++p)
            s += partial[((size_t)(b * 8 + p)) * 768 + i];
        av[i] = s * (1.0f / 512.0f);
    }
    __syncthreads();

    // matvec slice: j = j0 + (tid&127), k in [seg*384, seg*384+384)
    const int jl = threadIdx.x & 127;
    const int seg = threadIdx.x >> 7;
    const int j = j0 + jl;
    const float* Wp = Wts + (size_t)(seg * 384) * 768 + j;
    const float* avp = av + seg * 384;
    float a0 = 0.f, a1 = 0.f, a2 = 0.f, a3 = 0.f;
    float a4 = 0.f, a5 = 0.f, a6 = 0.f, a7 = 0.f;
#pragma unroll 4
    for (int k = 0; k < 384; k += 8) {
        a0 = fmaf(avp[k + 0], Wp[(size_t)(k + 0) * 768], a0);
        a1 = fmaf(avp[k + 1], Wp[(size_t)(k + 1) * 768], a1);
        a2 = fmaf(avp[k + 2], Wp[(size_t)(k + 2) * 768], a2);
        a3 = fmaf(avp[k + 3], Wp[(size_t)(k + 3) * 768], a3);
        a4 = fmaf(avp[k + 4], Wp[(size_t)(k + 4) * 768], a4);
        a5 = fmaf(avp[k + 5], Wp[(size_t)(k + 5) * 768], a5);
        a6 = fmaf(avp[k + 6], Wp[(size_t)(k + 6) * 768], a6);
        a7 = fmaf(avp[k + 7], Wp[(size_t)(k + 7) * 768], a7);
    }
    psum[seg][jl] = ((a0 + a1) + (a2 + a3)) + ((a4 + a5) + (a6 + a7));
    __syncthreads();

    // finish: alin = psum0+psum1+bias, then pairwise softmax
    if (threadIdx.x < 128)
        av[threadIdx.x] = psum[0][threadIdx.x] + psum[1][threadIdx.x]
                        + bts[j0 + threadIdx.x];
    __syncthreads();
    if (threadIdx.x < 64) {
        const int e = (j0 >> 1) + threadIdx.x;
        float x0 = av[2 * threadIdx.x], x1 = av[2 * threadIdx.x + 1];
        float m = fmaxf(x0, x1);
        float e0 = __expf(x0 - m), e1 = __expf(x1 - m);
        float inv = 1.f / (e0 + e1);
        gate[(size_t)b * 768 + e] = e0 * inv;
        gate[(size_t)b * 768 + 384 + e] = e1 * inv;
    }
}

// ---------------------------------------------------------------------------
// xg = bf16(xcat * gate[b]), 8 elems/thread
// ---------------------------------------------------------------------------
__global__ __launch_bounds__(256) void gate_mul(
    const ushort* __restrict__ xcat, const float* __restrict__ gate,
    ushort* __restrict__ xg)
{
    const int i = blockIdx.x * 256 + threadIdx.x;
    const int m = i / 96;
    const int k = (i % 96) * 8;
    const int b = m >> 9;
    uint4 u = ((const uint4*)xcat)[i];
    const float* g = gate + (size_t)b * 768 + k;
    float4 g0 = *(const float4*)g;
    float4 g1 = *(const float4*)(g + 4);
    uint4 o;
    o.x = pk2(lo2f(u.x) * g0.x, hi2f(u.x) * g0.y);
    o.y = pk2(lo2f(u.y) * g0.z, hi2f(u.y) * g0.w);
    o.z = pk2(lo2f(u.z) * g1.x, hi2f(u.z) * g1.y);
    o.w = pk2(lo2f(u.w) * g1.z, hi2f(u.w) * g1.w);
    ((uint4*)xg)[i] = o;
}

// ---------------------------------------------------------------------------
extern "C" void kernel_launch(void* const* d_in, const int* in_sizes, int n_in,
                              void* d_out, int out_size, void* d_ws, size_t ws_size,
                              hipStream_t stream)
{
    const float* x      = (const float*)d_in[0];
    const float* Wqkv_t = (const float*)d_in[1];
    const float* bqkv_t = (const float*)d_in[2];
    const float* Wqkv_s = (const float*)d_in[3];
    const float* bqkv_s = (const float*)d_in[4];
    const float* Wts    = (const float*)d_in[5];
    const float* bts    = (const float*)d_in[6];
    const float* Wfc_t  = (const float*)d_in[7];
    const float* bfc_t  = (const float*)d_in[8];
    const float* Wfc_s  = (const float*)d_in[9];
    const float* bfc_s  = (const float*)d_in[10];
    float* out = (float*)d_out;

    char* w = (char*)d_ws;
    ushort* qkvb   = (ushort*)(w);                 // 16384*1152 bf16
    ushort* xb     = (ushort*)(w + 37748736);      // 16384*768 bf16
    ushort* xcat   = (ushort*)(w + 62914560);      // 16384*768 bf16
    ushort* wbuf   = (ushort*)(w + 88080384);      // 1152*768 bf16
    ushort* xg     = (ushort*)(w + 89849856);      // 16384*768 bf16
    float*  partial= (float*)(w + 115015680);      // 32*8*768 f32
    float*  gate   = (float*)(w + 115802112);      // 32*768 f32

    const dim3 blk256(256);

    convert_bf16<<<dim3(6144), blk256, 0, stream>>>(x, xb);

    // temporal branch
    transpose_w<<<dim3(24, 36), blk256, 0, stream>>>(Wqkv_t, wbuf, 768, 1152, 768, 0);
    gemm_mfma<1, 1><<<dim3(128, 9), blk256, 0, stream>>>(
        xb, wbuf, bqkv_t, nullptr, qkvb, 16384, 1152, 768);
    attn_temporal<<<dim3(4, 8, 32), blk256, 0, stream>>>(qkvb, xcat);

    // spatial branch (reuses qkvb + wbuf)
    transpose_w<<<dim3(24, 36), blk256, 0, stream>>>(Wqkv_s, wbuf, 768, 1152, 768, 0);
    gemm_mfma<1, 1><<<dim3(128, 9), blk256, 0, stream>>>(
        xb, wbuf, bqkv_s, nullptr, qkvb, 16384, 1152, 768);
    attn_spatial<<<dim3(16384), dim3(192), 0, stream>>>(qkvb, xcat);

    // gating
    colsum<<<dim3(32, 3, 8), blk256, 0, stream>>>(xcat, partial);
    alpha_gate<<<dim3(32, 6), blk256, 0, stream>>>(partial, Wts, bts, gate);
    gate_mul<<<dim3(6144), blk256, 0, stream>>>(xcat, gate, xg);

    // final fused GEMM: Bt = [Wfc_t; Wfc_s]^T -> [768 n][768 k]
    transpose_w<<<dim3(12, 24), blk256, 0, stream>>>(Wfc_t, wbuf, 384, 768, 768, 0);
    transpose_w<<<dim3(12, 24), blk256, 0, stream>>>(Wfc_s, wbuf, 384, 768, 768, 384);
    gemm_mfma<0, 2><<<dim3(128, 6), blk256, 0, stream>>>(
        xg, wbuf, bfc_t, bfc_s, out, 16384, 768, 768);
}

// Round 5
// 243.845 us; speedup vs baseline: 5.2174x; 1.1131x over previous
//
#include <hip/hip_runtime.h>
#include <hip/hip_bf16.h>

// B=32, N=512, H=8, DH=48, E=384, IN=768, R=16384, QKV cols=1152

typedef __attribute__((ext_vector_type(8))) short s16x8;
typedef __attribute__((ext_vector_type(4))) float f32x4;

__device__ __forceinline__ float lo2f(uint u) { return __uint_as_float(u << 16); }
__device__ __forceinline__ float hi2f(uint u) { return __uint_as_float(u & 0xffff0000u); }
__device__ __forceinline__ ushort f2bu(float f) {
    union { __hip_bfloat16 h; ushort u; } c; c.h = __float2bfloat16(f); return c.u;
}
__device__ __forceinline__ uint pk2(float a, float b) {
    return (uint)f2bu(a) | ((uint)f2bu(b) << 16);
}
__device__ __forceinline__ void gload16(const void* g, void* l) {
    __builtin_amdgcn_global_load_lds((const __attribute__((address_space(1))) void*)g,
                                     (__attribute__((address_space(3))) void*)l, 16, 0, 0);
}

// ---------------------------------------------------------------------------
// fp32 -> bf16 convert, 8 elems/thread
// ---------------------------------------------------------------------------
__global__ __launch_bounds__(256) void convert_bf16(
    const float* __restrict__ in, ushort* __restrict__ out)
{
    const int i = blockIdx.x * 256 + threadIdx.x;
    const float4* p = (const float4*)in + (size_t)i * 2;
    float4 a = p[0], b = p[1];
    uint4 o;
    o.x = pk2(a.x, a.y); o.y = pk2(a.z, a.w);
    o.z = pk2(b.x, b.y); o.w = pk2(b.z, b.w);
    ((uint4*)out)[i] = o;
}

// ---------------------------------------------------------------------------
// Transpose+convert: W fp32 [K][N] -> Bt bf16 [N][Kt] (k written at koff)
// ---------------------------------------------------------------------------
__global__ __launch_bounds__(256) void transpose_w(
    const float* __restrict__ W, ushort* __restrict__ Bt,
    int K, int N, int Kt, int koff)
{
    __shared__ float t[32][33];
    const int k0 = blockIdx.x * 32, n0 = blockIdx.y * 32;
    const int r = threadIdx.x >> 3, cq = threadIdx.x & 7;
    float4 v = *(const float4*)(W + (size_t)(k0 + r) * N + n0 + cq * 4);
    t[r][cq * 4 + 0] = v.x; t[r][cq * 4 + 1] = v.y;
    t[r][cq * 4 + 2] = v.z; t[r][cq * 4 + 3] = v.w;
    __syncthreads();
    ushort4 o;
    o.x = f2bu(t[cq * 4 + 0][r]); o.y = f2bu(t[cq * 4 + 1][r]);
    o.z = f2bu(t[cq * 4 + 2][r]); o.w = f2bu(t[cq * 4 + 3][r]);
    *(ushort4*)(Bt + (size_t)(n0 + r) * Kt + koff + k0 + cq * 4) = o;
}

// ---------------------------------------------------------------------------
// bf16 MFMA GEMM: C = A[M][K] @ Bt[N][K]^T + bias. 128x128 tile, BK=64.
// LDS [128][64] with 16B-block XOR swizzle (blk ^= row&7) applied via
// pre-swizzled GLOBAL source (gload_lds dest stays wave-linear, m173).
// GATED: A is multiplied elementwise by gate[b][k] during staging (reg-path).
// ---------------------------------------------------------------------------
template<int OUTBF16, int NBIAS, int GATED>
__global__ __launch_bounds__(256) void gemm_mfma(
    const ushort* __restrict__ A, const ushort* __restrict__ Bt,
    const float* __restrict__ bias0, const float* __restrict__ bias1,
    const float* __restrict__ gate, void* __restrict__ Cout,
    int M, int N, int K)
{
    __shared__ ushort As[8192];   // [128][64]
    __shared__ ushort Bs[8192];
    __shared__ float gs[GATED ? 768 : 1];
    const int tid = threadIdx.x;
    const int m0 = blockIdx.x * 128;
    const int n0 = blockIdx.y * 128;
    const int lane = tid & 63;
    const int wr = tid >> 7;
    const int wc = (tid >> 6) & 1;
    const int lr = lane & 15;
    const int kh = lane >> 4;

    if (GATED) {
        const float* gsrc = gate + (size_t)(m0 >> 9) * 768;
        for (int i = tid; i < 768; i += 256) gs[i] = gsrc[i];
        __syncthreads();
    }

    f32x4 acc[4][4];
#pragma unroll
    for (int i = 0; i < 4; ++i)
#pragma unroll
        for (int j = 0; j < 4; ++j) acc[i][j] = (f32x4){0.f, 0.f, 0.f, 0.f};

    // staging geometry: task = tid + 256*i -> row = task>>3, kq = task&7.
    // global source chunk is kq ^ (row&7); LDS slot stays linear (task*8).
    int rowT[4], kqs[4];
#pragma unroll
    for (int i = 0; i < 4; ++i) {
        const int task = tid + 256 * i;
        rowT[i] = task >> 3;
        kqs[i] = (task & 7) ^ (rowT[i] & 7);
    }

    for (int k0 = 0; k0 < K; k0 += 64) {
        if (!GATED) {
#pragma unroll
            for (int i = 0; i < 4; ++i)
                gload16(A + (size_t)(m0 + rowT[i]) * K + k0 + (kqs[i] << 3),
                        &As[(tid + 256 * i) * 8]);
        } else {
            uint4 va[4];
#pragma unroll
            for (int i = 0; i < 4; ++i)
                va[i] = *(const uint4*)(A + (size_t)(m0 + rowT[i]) * K + k0 + (kqs[i] << 3));
#pragma unroll
            for (int i = 0; i < 4; ++i) {
                const float* gp = &gs[k0 + (kqs[i] << 3)];
                uint4 o;
                o.x = pk2(lo2f(va[i].x) * gp[0], hi2f(va[i].x) * gp[1]);
                o.y = pk2(lo2f(va[i].y) * gp[2], hi2f(va[i].y) * gp[3]);
                o.z = pk2(lo2f(va[i].z) * gp[4], hi2f(va[i].z) * gp[5]);
                o.w = pk2(lo2f(va[i].w) * gp[6], hi2f(va[i].w) * gp[7]);
                *(uint4*)&As[(tid + 256 * i) * 8] = o;
            }
        }
#pragma unroll
        for (int i = 0; i < 4; ++i)
            gload16(Bt + (size_t)(n0 + rowT[i]) * K + k0 + (kqs[i] << 3),
                    &Bs[(tid + 256 * i) * 8]);
        __syncthreads();
#pragma unroll
        for (int half = 0; half < 2; ++half) {
            s16x8 af[4], bfv[4];
#pragma unroll
            for (int i = 0; i < 4; ++i)
                af[i] = *(const s16x8*)&As[(wr * 64 + 16 * i + lr) * 64
                                           + (((4 * half + kh) ^ (lr & 7)) << 3)];
#pragma unroll
            for (int j = 0; j < 4; ++j)
                bfv[j] = *(const s16x8*)&Bs[(wc * 64 + 16 * j + lr) * 64
                                            + (((4 * half + kh) ^ (lr & 7)) << 3)];
#pragma unroll
            for (int i = 0; i < 4; ++i)
#pragma unroll
                for (int j = 0; j < 4; ++j)
                    acc[i][j] = __builtin_amdgcn_mfma_f32_16x16x32_bf16(
                        af[i], bfv[j], acc[i][j], 0, 0, 0);
        }
        __syncthreads();
    }

    const int r0 = m0 + wr * 64 + (lane >> 4) * 4;
    const int c0 = n0 + wc * 64 + lr;
#pragma unroll
    for (int j = 0; j < 4; ++j) {
        const int col = c0 + j * 16;
        float bsum = bias0[col];
        if (NBIAS == 2) bsum += bias1[col];
#pragma unroll
        for (int i = 0; i < 4; ++i) {
            const int row = r0 + i * 16;
#pragma unroll
            for (int v = 0; v < 4; ++v) {
                const float val = acc[i][j][v] + bsum;
                if (OUTBF16)
                    ((ushort*)Cout)[(size_t)(row + v) * N + col] = f2bu(val);
                else
                    ((float*)Cout)[(size_t)(row + v) * N + col] = val;
            }
        }
    }
}

// ---------------------------------------------------------------------------
// Temporal flash attention, MFMA. Grid 1024 (XCD-remapped), 256 thr = 4 waves.
// K staged [kv][64] and V^T staged [d][64], both 16B-block XOR swizzled
// (write and read use the same involution -> all LDS ops <=2-way).
// Register prefetch of next K/V tile overlaps compute (T14).
// ---------------------------------------------------------------------------
__global__ __launch_bounds__(256, 4) void attn_temporal(
    const ushort* __restrict__ qkv, ushort* __restrict__ xcat)
{
    // XCD-bijective remap: the 4 q-tiles of one (h,b) land on the same XCD
    const int wg = blockIdx.x;
    const int cx = wg & 7, rx = wg >> 3;
    const int id = ((rx >> 2) << 5) + 4 * cx + (rx & 3);
    const int qt = id & 3;
    const int h = (id >> 2) & 7;
    const int b = id >> 5;

    const int tid = threadIdx.x;
    const int w = tid >> 6;
    const int lane = tid & 63;
    const int lr = lane & 15;
    const int g = lane >> 4;

    __shared__ ushort Ks[64 * 64];      // [kv][d], d cols 48..63 zero
    __shared__ ushort Vt[48 * 64];      // [d][kv]
    __shared__ ushort Pl[4][32 * 72];   // per wave: [q][72], col = kv
    __shared__ float statsL[4][32];
    uint* KsU = (uint*)Ks;
    uint* VtU = (uint*)Vt;

    // zero Ks once (pad cols stay zero: staging never writes dw>=24 slots)
    ((uint4*)Ks)[tid] = make_uint4(0u, 0u, 0u, 0u);
    ((uint4*)Ks)[256 + tid] = make_uint4(0u, 0u, 0u, 0u);
    __syncthreads();

    const uint* qkvu = (const uint*)qkv;
    const int qrow0 = qt * 128 + w * 32;

    // Q B-frags from global: q row = qrow0+16n+lr, d = 8g (+32 for ks=1)
    s16x8 qf[2][2];
#pragma unroll
    for (int n = 0; n < 2; ++n) {
        const size_t rb = (size_t)(b * 512 + qrow0 + 16 * n + lr) * 1152 + h * 48 + 8 * g;
        qf[n][0] = *(const s16x8*)(qkv + rb);
        qf[n][1] = (g < 2) ? *(const s16x8*)(qkv + rb + 32)
                           : (s16x8){0, 0, 0, 0, 0, 0, 0, 0};
    }

    // staging decomposition: 768 tasks = 32 row-pairs x 24 dwords
    int p_[3], du_[3];
#pragma unroll
    for (int i = 0; i < 3; ++i) {
        const int idx = tid + 256 * i;
        p_[i] = idx / 24;
        du_[i] = idx % 24;
    }
    uint rk[3][2], rv[3][2];

    auto stage_load = [&](int kv0) {
#pragma unroll
        for (int i = 0; i < 3; ++i) {
            const uint* s0 = qkvu + (size_t)(b * 512 + kv0 + 2 * p_[i]) * 576
                                  + 192 + h * 24 + du_[i];
            rk[i][0] = s0[0];   rk[i][1] = s0[576];
            rv[i][0] = s0[192]; rv[i][1] = s0[768];
        }
    };
    auto stage_write = [&]() {
#pragma unroll
        for (int i = 0; i < 3; ++i) {
            const int p = p_[i], du = du_[i];
            KsU[(2 * p) * 32 + ((((du >> 2) ^ ((2 * p) & 7)) << 2) | (du & 3))] = rk[i][0];
            KsU[(2 * p + 1) * 32 + ((((du >> 2) ^ ((2 * p + 1) & 7)) << 2) | (du & 3))] = rk[i][1];
            const uint w0 = (rv[i][0] & 0xffffu) | (rv[i][1] << 16);
            const uint w1 = (rv[i][0] >> 16) | (rv[i][1] & 0xffff0000u);
            const int vb = (((p >> 2) ^ (du & 7)) << 2) | (p & 3);
            VtU[(2 * du) * 32 + vb] = w0;
            VtU[(2 * du + 1) * 32 + vb] = w1;
        }
    };

    f32x4 o[2][3];
#pragma unroll
    for (int mq = 0; mq < 2; ++mq)
#pragma unroll
        for (int nd = 0; nd < 3; ++nd) o[mq][nd] = (f32x4){0.f, 0.f, 0.f, 0.f};
    float mrun[2] = {-3.0e38f, -3.0e38f};
    float lsum[2] = {0.f, 0.f};
    const float scale = 0.14433756729740643f; // 1/sqrt(48)

    stage_load(0);
    stage_write();
    __syncthreads();

    for (int t = 0; t < 8; ++t) {
        if (t < 7) stage_load((t + 1) * 64);   // prefetch overlaps compute

        // ---- QK^T (swapped): sa[m][n], kv = 16m+4g+v, q = 16n+lr ----
        f32x4 sa[4][2];
#pragma unroll
        for (int m = 0; m < 4; ++m)
#pragma unroll
            for (int n = 0; n < 2; ++n) sa[m][n] = (f32x4){0.f, 0.f, 0.f, 0.f};
#pragma unroll
        for (int ks = 0; ks < 2; ++ks)
#pragma unroll
            for (int m = 0; m < 4; ++m) {
                s16x8 kf = *(const s16x8*)&Ks[(16 * m + lr) * 64
                                              + (((g + 4 * ks) ^ (lr & 7)) << 3)];
#pragma unroll
                for (int n = 0; n < 2; ++n)
                    sa[m][n] = __builtin_amdgcn_mfma_f32_16x16x32_bf16(
                        kf, qf[n][ks], sa[m][n], 0, 0, 0);
            }

        // ---- online softmax; write P (bf16) to per-wave LDS ----
#pragma unroll
        for (int n = 0; n < 2; ++n) {
            float tmax = -3.0e38f;
#pragma unroll
            for (int m = 0; m < 4; ++m)
#pragma unroll
                for (int v = 0; v < 4; ++v) tmax = fmaxf(tmax, sa[m][n][v]);
            tmax = fmaxf(tmax, __shfl_xor(tmax, 16));
            tmax = fmaxf(tmax, __shfl_xor(tmax, 32));
            float mnew = fmaxf(mrun[n], tmax * scale);
            float corr = __expf(mrun[n] - mnew);
            mrun[n] = mnew;
            float psum = 0.f;
#pragma unroll
            for (int m = 0; m < 4; ++m) {
                float p0 = __expf(fmaf(sa[m][n][0], scale, -mnew));
                float p1 = __expf(fmaf(sa[m][n][1], scale, -mnew));
                float p2 = __expf(fmaf(sa[m][n][2], scale, -mnew));
                float p3 = __expf(fmaf(sa[m][n][3], scale, -mnew));
                psum += (p0 + p1) + (p2 + p3);
                const int base = (16 * n + lr) * 72 + 16 * m + 4 * g;
                *(uint*)&Pl[w][base] = pk2(p0, p1);
                *(uint*)&Pl[w][base + 2] = pk2(p2, p3);
            }
            psum += __shfl_xor(psum, 16);
            psum += __shfl_xor(psum, 32);
            lsum[n] = lsum[n] * corr + psum;
            if (g == 0) statsL[w][16 * n + lr] = corr;
        }

        // ---- rescale O by per-q corr (row-indexed lanes) ----
        f32x4 corr4[2];
#pragma unroll
        for (int mq = 0; mq < 2; ++mq)
            corr4[mq] = *(const f32x4*)&statsL[w][16 * mq + 4 * g];
#pragma unroll
        for (int mq = 0; mq < 2; ++mq)
#pragma unroll
            for (int nd = 0; nd < 3; ++nd)
#pragma unroll
                for (int v = 0; v < 4; ++v) o[mq][nd][v] *= corr4[mq][v];

        // ---- PV: o[mq][nd] += P[q][kv] @ V[kv][d] ----
#pragma unroll
        for (int ks = 0; ks < 2; ++ks) {
            s16x8 vf[3];
#pragma unroll
            for (int nd = 0; nd < 3; ++nd)
                vf[nd] = *(const s16x8*)&Vt[(16 * nd + lr) * 64
                                            + (((g + 4 * ks) ^ (lr >> 1)) << 3)];
#pragma unroll
            for (int mq = 0; mq < 2; ++mq) {
                s16x8 pf = *(const s16x8*)&Pl[w][(16 * mq + lr) * 72 + 8 * g + 32 * ks];
#pragma unroll
                for (int nd = 0; nd < 3; ++nd)
                    o[mq][nd] = __builtin_amdgcn_mfma_f32_16x16x32_bf16(
                        pf, vf[nd], o[mq][nd], 0, 0, 0);
            }
        }
        __syncthreads();
        if (t < 7) stage_write();
        __syncthreads();
    }

    // ---- finalize ----
    if (g == 0) { statsL[w][lr] = lsum[0]; statsL[w][16 + lr] = lsum[1]; }
    f32x4 linv[2];
#pragma unroll
    for (int mq = 0; mq < 2; ++mq) {
        f32x4 lv = *(const f32x4*)&statsL[w][16 * mq + 4 * g];
#pragma unroll
        for (int v = 0; v < 4; ++v) linv[mq][v] = 1.f / lv[v];
    }
#pragma unroll
    for (int mq = 0; mq < 2; ++mq)
#pragma unroll
        for (int v = 0; v < 4; ++v) {
            const int qrow = qrow0 + 16 * mq + 4 * g + v;
            ushort* dst = xcat + (size_t)(b * 512 + qrow) * 768 + h * 48;
#pragma unroll
            for (int nd = 0; nd < 3; ++nd)
                dst[16 * nd + lr] = f2bu(o[mq][nd][v] * linv[mq][v]);
        }
}

// ---------------------------------------------------------------------------
// Spatial attention (unscaled logits). One block per g. 192 thr = 8h x 24t.
// ---------------------------------------------------------------------------
__global__ __launch_bounds__(192) void attn_spatial(
    const ushort* __restrict__ qkv, ushort* __restrict__ xcat)
{
    const int g = blockIdx.x;
    __shared__ float row[1152];
    const uint* qkvu = (const uint*)qkv;
#pragma unroll
    for (int i = 0; i < 3; ++i) {
        int idx = threadIdx.x + 192 * i;
        uint u = qkvu[(size_t)g * 576 + idx];
        row[2 * idx] = lo2f(u); row[2 * idx + 1] = hi2f(u);
    }
    __syncthreads();

    const int h = threadIdx.x / 24;
    const int t = threadIdx.x % 24;
    const float* q = &row[h * 48];
    const float* k = &row[384 + h * 48];
    const float* v = &row[768 + h * 48];
    const float q0 = q[t], q1 = q[24 + t];

    float s[24];
    float mx = -3.0e38f;
#pragma unroll
    for (int u = 0; u < 24; ++u) {
        s[u] = q0 * k[u] + q1 * k[24 + u];
        mx = fmaxf(mx, s[u]);
    }
    float l = 0.f;
#pragma unroll
    for (int u = 0; u < 24; ++u) { s[u] = __expf(s[u] - mx); l += s[u]; }
    const float inv = 1.f / l;
    float o0 = 0.f, o1 = 0.f;
#pragma unroll
    for (int u = 0; u < 24; ++u) {
        o0 = fmaf(s[u], v[u], o0);
        o1 = fmaf(s[u], v[24 + u], o1);
    }
    ushort* dst = xcat + (size_t)g * 768 + 384 + h * 48;
    dst[t] = f2bu(o0 * inv);
    dst[24 + t] = f2bu(o1 * inv);
}

// ---------------------------------------------------------------------------
// Column partial sums (bf16 in, fp32 out). grid (32,3,8).
// ---------------------------------------------------------------------------
__global__ __launch_bounds__(256) void colsum(
    const ushort* __restrict__ xcat, float* __restrict__ partial)
{
    const int b = blockIdx.x, ch = blockIdx.y, part = blockIdx.z;
    const int e = ch * 256 + threadIdx.x;
    const int n0 = part * 64;
    float s = 0.f;
    for (int n = 0; n < 64; ++n)
        s += __uint_as_float((uint)xcat[((size_t)(b * 512 + n0 + n)) * 768 + e] << 16);
    partial[((size_t)(b * 8 + part)) * 768 + e] = s;
}

// ---------------------------------------------------------------------------
// Gating, parallel. grid (32 b, 6 j-tiles of 128), 256 thr.
// ---------------------------------------------------------------------------
__global__ __launch_bounds__(256) void alpha_gate(
    const float* __restrict__ partial, const float* __restrict__ Wts,
    const float* __restrict__ bts, float* __restrict__ gate)
{
    const int b = blockIdx.x;
    const int j0 = blockIdx.y * 128;
    __shared__ float av[768];
    __shared__ float psum[2][128];

    for (int i = threadIdx.x; i < 768; i += 256) {
        float s = 0.f;
#pragma unroll
        for (int p = 0; p < 8; ++p)
            s += partial[((size_t)(b * 8 + p)) * 768 + i];
        av[i] = s * (1.0f / 512.0f);
    }
    __syncthreads();

    const int jl = threadIdx.x & 127;
    const int seg = threadIdx.x >> 7;
    const int j = j0 + jl;
    const float* Wp = Wts + (size_t)(seg * 384) * 768 + j;
    const float* avp = av + seg * 384;
    float a0 = 0.f, a1 = 0.f, a2 = 0.f, a3 = 0.f;
    float a4 = 0.f, a5 = 0.f, a6 = 0.f, a7 = 0.f;
#pragma unroll 4
    for (int k = 0; k < 384; k += 8) {
        a0 = fmaf(avp[k + 0], Wp[(size_t)(k + 0) * 768], a0);
        a1 = fmaf(avp[k + 1], Wp[(size_t)(k + 1) * 768], a1);
        a2 = fmaf(avp[k + 2], Wp[(size_t)(k + 2) * 768], a2);
        a3 = fmaf(avp[k + 3], Wp[(size_t)(k + 3) * 768], a3);
        a4 = fmaf(avp[k + 4], Wp[(size_t)(k + 4) * 768], a4);
        a5 = fmaf(avp[k + 5], Wp[(size_t)(k + 5) * 768], a5);
        a6 = fmaf(avp[k + 6], Wp[(size_t)(k + 6) * 768], a6);
        a7 = fmaf(avp[k + 7], Wp[(size_t)(k + 7) * 768], a7);
    }
    psum[seg][jl] = ((a0 + a1) + (a2 + a3)) + ((a4 + a5) + (a6 + a7));
    __syncthreads();

    if (threadIdx.x < 128)
        av[threadIdx.x] = psum[0][threadIdx.x] + psum[1][threadIdx.x]
                        + bts[j0 + threadIdx.x];
    __syncthreads();
    if (threadIdx.x < 64) {
        const int e = (j0 >> 1) + threadIdx.x;
        float x0 = av[2 * threadIdx.x], x1 = av[2 * threadIdx.x + 1];
        float m = fmaxf(x0, x1);
        float e0 = __expf(x0 - m), e1 = __expf(x1 - m);
        float inv = 1.f / (e0 + e1);
        gate[(size_t)b * 768 + e] = e0 * inv;
        gate[(size_t)b * 768 + 384 + e] = e1 * inv;
    }
}

// ---------------------------------------------------------------------------
extern "C" void kernel_launch(void* const* d_in, const int* in_sizes, int n_in,
                              void* d_out, int out_size, void* d_ws, size_t ws_size,
                              hipStream_t stream)
{
    const float* x      = (const float*)d_in[0];
    const float* Wqkv_t = (const float*)d_in[1];
    const float* bqkv_t = (const float*)d_in[2];
    const float* Wqkv_s = (const float*)d_in[3];
    const float* bqkv_s = (const float*)d_in[4];
    const float* Wts    = (const float*)d_in[5];
    const float* bts    = (const float*)d_in[6];
    const float* Wfc_t  = (const float*)d_in[7];
    const float* bfc_t  = (const float*)d_in[8];
    const float* Wfc_s  = (const float*)d_in[9];
    const float* bfc_s  = (const float*)d_in[10];
    float* out = (float*)d_out;

    char* w = (char*)d_ws;
    ushort* qkvb   = (ushort*)(w);                 // 16384*1152 bf16
    ushort* xb     = (ushort*)(w + 37748736);      // 16384*768 bf16
    ushort* xcat   = (ushort*)(w + 62914560);      // 16384*768 bf16
    ushort* wbuf   = (ushort*)(w + 88080384);      // 1152*768 bf16
    float*  partial= (float*)(w + 115015680);      // 32*8*768 f32
    float*  gate   = (float*)(w + 115802112);      // 32*768 f32

    const dim3 blk256(256);

    convert_bf16<<<dim3(6144), blk256, 0, stream>>>(x, xb);

    // temporal branch
    transpose_w<<<dim3(24, 36), blk256, 0, stream>>>(Wqkv_t, wbuf, 768, 1152, 768, 0);
    gemm_mfma<1, 1, 0><<<dim3(128, 9), blk256, 0, stream>>>(
        xb, wbuf, bqkv_t, nullptr, nullptr, qkvb, 16384, 1152, 768);
    attn_temporal<<<dim3(1024), blk256, 0, stream>>>(qkvb, xcat);

    // spatial branch (reuses qkvb + wbuf)
    transpose_w<<<dim3(24, 36), blk256, 0, stream>>>(Wqkv_s, wbuf, 768, 1152, 768, 0);
    gemm_mfma<1, 1, 0><<<dim3(128, 9), blk256, 0, stream>>>(
        xb, wbuf, bqkv_s, nullptr, nullptr, qkvb, 16384, 1152, 768);
    attn_spatial<<<dim3(16384), dim3(192), 0, stream>>>(qkvb, xcat);

    // gating
    colsum<<<dim3(32, 3, 8), blk256, 0, stream>>>(xcat, partial);
    alpha_gate<<<dim3(32, 6), blk256, 0, stream>>>(partial, Wts, bts, gate);

    // final fused gated GEMM: Bt = [Wfc_t; Wfc_s]^T -> [768 n][768 k]
    transpose_w<<<dim3(12, 24), blk256, 0, stream>>>(Wfc_t, wbuf, 384, 768, 768, 0);
    transpose_w<<<dim3(12, 24), blk256, 0, stream>>>(Wfc_s, wbuf, 384, 768, 768, 384);
    gemm_mfma<0, 2, 1><<<dim3(128, 6), blk256, 0, stream>>>(
        xcat, wbuf, bfc_t, bfc_s, gate, out, 16384, 768, 768);
}